// Round 12
// baseline (833.224 us; speedup 1.0000x reference)
//
#include <hip/hip_runtime.h>
#include <hip/hip_bf16.h>

typedef __attribute__((ext_vector_type(8))) short short8;
typedef __attribute__((ext_vector_type(4))) float f32x4;
typedef __attribute__((ext_vector_type(2))) float f32x2;
typedef __attribute__((ext_vector_type(4))) int int32x4;

// raw buffer load: 32-bit voffset addressing (no per-lane 64-bit addr VALU)
__device__ unsigned int llvm_amdgcn_raw_buffer_load_u32(int32x4 srsrc, int voffset,
                                                        int soffset, int aux)
    __asm("llvm.amdgcn.raw.buffer.load.i32");

#define VOXELS 262144  // 64^3
#define ZC_PAD 264
#define Z0_PAD 72
#define Z2_PAD 520
#define Z3_PAD 264
#define RA_PAD 872     // rowA stride: 1744 B -> 2-way bank alias only (free)
#define NCELL  512     // 8x8x8 Morton cells

// ---------------- volume transpose: (C,D,H,W) -> (D,H,W,C) ----------------
template <bool VT16>
__global__ void k_transpose(const float* __restrict__ v0, const float* __restrict__ v1,
                            const float* __restrict__ v2, const float* __restrict__ v3,
                            void* __restrict__ vtp) {
    int b  = blockIdx.x;
    int q  = b >> 12;
    int zy = b & 4095;
    const float* src = (q == 0) ? v0 : (q == 1) ? v1 : (q == 2) ? v2 : v3;
    __shared__ float buf[32][65];
    int t = threadIdx.x;
    int x = t & 63, c0 = t >> 6;
    for (int cp = 0; cp < 32; cp += 4) {
        int c = c0 + cp;
        buf[c][x] = src[(size_t)c * VOXELS + (size_t)zy * 64 + x];
    }
    __syncthreads();
    int c = t & 31, xg = t >> 5;
    const size_t base = ((size_t)q * VOXELS + (size_t)zy * 64) * 32;
    for (int xx = xg; xx < 64; xx += 8) {
        if (VT16) ((__hip_bfloat16*)vtp)[base + xx * 32 + c] = __float2bfloat16(buf[c][xx]);
        else      ((float*)vtp)[base + xx * 32 + c] = buf[c][xx];
    }
}

// ------------- merged weight pack: all 5 weight tensors in ONE launch -------------
__device__ __forceinline__ void prep_one(const float* __restrict__ W,
                                         __hip_bfloat16* __restrict__ wf,
                                         int K, int mode, int n) {
    int e = n & 7, lane = (n >> 3) & 63;
    int rest = n >> 9;
    int ksteps = K >> 5;
    int kstep = rest % ksteps, otile = rest / ksteps;
    int o = otile * 16 + (lane & 15);
    int k = kstep * 32 + (lane >> 4) * 8 + e;
    float v;
    if (mode == 1)      v = W[(size_t)o * K + (k & 31) * 27 + (k >> 5)];
    else if (mode == 2) v = (o < 3) ? W[(size_t)o * K + k] : 0.f;
    else                v = W[(size_t)o * K + k];
    wf[n] = __float2bfloat16(v);
}

__global__ void k_prepw_all(const float* __restrict__ conv_w, const float* __restrict__ lfc_w,
                            const float* __restrict__ fc2_w, const float* __restrict__ fc3_w,
                            const float* __restrict__ fc4_w,
                            __hip_bfloat16* __restrict__ w0f, __hip_bfloat16* __restrict__ w1f,
                            __hip_bfloat16* __restrict__ w2f, __hip_bfloat16* __restrict__ w3f,
                            __hip_bfloat16* __restrict__ w4f) {
    int n = blockIdx.x * blockDim.x + threadIdx.x;
    if (n < 55296)                prep_one(conv_w, w0f, 864, 1, n);
    else if (n < 63488)           prep_one(lfc_w,  w1f, 64,  0, n - 55296);
    else if (n < 194560)          prep_one(fc2_w,  w2f, 256, 0, n - 63488);
    else if (n < 325632)          prep_one(fc3_w,  w3f, 512, 0, n - 194560);
    else if (n < 329728)          prep_one(fc4_w,  w4f, 256, 2, n - 325632);
}

// ================= spatial sort (counting sort by Morton cell) =================
__device__ __forceinline__ int point_cell(float px, float py, float pz) {
    int cx = min(63, max(0, (int)(px * 31.5f + 31.5f))) >> 3;
    int cy = min(63, max(0, (int)(py * 31.5f + 31.5f))) >> 3;
    int cz = min(63, max(0, (int)(pz * 31.5f + 31.5f))) >> 3;
    int k = 0;
#pragma unroll
    for (int b = 0; b < 3; ++b)
        k |= (((cx >> b) & 1) << (3 * b)) | (((cy >> b) & 1) << (3 * b + 1))
           | (((cz >> b) & 1) << (3 * b + 2));
    return k;
}

__global__ void k_hist(const float* __restrict__ xin, int* __restrict__ hist, int m) {
    int p = blockIdx.x * blockDim.x + threadIdx.x;
    if (p >= m) return;
    atomicAdd(&hist[point_cell(xin[p * 3], xin[p * 3 + 1], xin[p * 3 + 2])], 1);
}

// single-wave exclusive scan of 512 cells
__global__ __launch_bounds__(64)
void k_scan(const int* __restrict__ hist, int* __restrict__ cursor) {
    const int t = threadIdx.x;
    int vals[8];
    int s = 0;
#pragma unroll
    for (int k = 0; k < 8; ++k) { vals[k] = hist[t * 8 + k]; s += vals[k]; }
    int pre = s;
#pragma unroll
    for (int off = 1; off < 64; off <<= 1) {
        int u = __shfl_up(pre, off);
        if (t >= off) pre += u;
    }
    int run = pre - s;
#pragma unroll
    for (int k = 0; k < 8; ++k) { cursor[t * 8 + k] = run; run += vals[k]; }
}

__global__ void k_scatter(const float* __restrict__ xin, int* __restrict__ cursor,
                          int* __restrict__ perm, int m) {
    int p = blockIdx.x * blockDim.x + threadIdx.x;
    if (p >= m) return;
    int cell = point_cell(xin[p * 3], xin[p * 3 + 1], xin[p * 3 + 2]);
    int pos = atomicAdd(&cursor[cell], 1);
    perm[pos] = p;
}

// ================= fully fused: sample (-> LDS) + MLP, 32 pts/block =================
// r12: kills the fbuf round-trip (86 MB NT write + re-read) and overlaps the
// VALU-bound sampler with the MFMA/latency-bound MLP across 2 resident blocks
// (m114: separate pipes co-schedule). 16 waves: phase1 = 2 pts/wave sampled
// straight into rowA LDS; then r11's proven MLP tiling. rowA (55.8 KB)
// unioned with z2l+z3l (dead until fc2). LDS 77.3 KB -> 2 blocks/CU,
// 32 waves/CU; __launch_bounds__(1024,8) caps VGPR at 64 (sampler was 56).
template <bool VT16, bool SORT>
__global__ __launch_bounds__(1024, 8)
void k_all(const float* __restrict__ xin, const void* __restrict__ vtp,
           const int* __restrict__ perm,
           const __hip_bfloat16* __restrict__ w0f, const float* __restrict__ b0,
           const __hip_bfloat16* __restrict__ w1f, const float* __restrict__ b1,
           const float* __restrict__ fc1w, const float* __restrict__ fc1b,
           const __hip_bfloat16* __restrict__ w2f, const float* __restrict__ b2,
           const __hip_bfloat16* __restrict__ w3f, const float* __restrict__ b3,
           const __hip_bfloat16* __restrict__ w4f, const float* __restrict__ fc4b,
           float* __restrict__ out, int m, int nblk) {
    __shared__ __align__(16) __hip_bfloat16 zcat[32][ZC_PAD];   // 16.9 KB
    __shared__ __align__(16) __hip_bfloat16 z0l[32][Z0_PAD];    //  4.6 KB
    __shared__ __align__(16) char shr[32 * 1744];               // 55.8 KB union
    __hip_bfloat16 (*rowA)[RA_PAD]  = (__hip_bfloat16(*)[RA_PAD])shr;      // phase1+conv
    __hip_bfloat16 (*z2l)[Z2_PAD]   = (__hip_bfloat16(*)[Z2_PAD])shr;      // fc2+
    __hip_bfloat16 (*z3l)[Z3_PAD]   = (__hip_bfloat16(*)[Z3_PAD])(shr + 33280);

    // bijective XCD swizzle: contiguous chunk of sorted points per XCD
    int b = blockIdx.x;
    {
        const int qd = nblk >> 3, r = nblk & 7;
        const int xcd = b & 7, i = b >> 3;
        b = (xcd < r) ? xcd * (qd + 1) + i : r * (qd + 1) + (xcd - r) * qd + i;
    }
    const int tid  = threadIdx.x;
    const int wave = tid >> 6;     // 0..15
    const int lane = tid & 63;
    const int p0   = b * 32;
    const int row  = lane & 15, g = lane >> 4;

    // ============ phase 1: sampling — 2 points per wave, straight to LDS ============
    {
        const int pr  = lane & 15;         // channel pair
        const int cxb = (lane >> 4) & 1;   // x corner
        const int cyb = (lane >> 5) & 1;   // y corner

        const int XS  = VT16 ? 6 : 7;
        const int YS  = VT16 ? 12 : 13;
        const int ZS  = VT16 ? 18 : 19;
        const int QS  = VT16 ? 24 : 25;
        const int PRB = VT16 ? 4 : 8;

        int32x4 srsrc;
        srsrc.x = (int)(unsigned)(uintptr_t)vtp;
        srsrc.y = (int)((uintptr_t)vtp >> 32);
        srsrc.z = -1;
        srsrc.w = 0x00020000;
        const char* __restrict__ vtb = (const char*)vtp;

#pragma unroll 1
        for (int rep = 0; rep < 2; ++rep) {
            const int pt = wave + rep * 16;
            const int sp = min(p0 + pt, m - 1);
            const int p  = SORT ? perm[sp] : sp;

            const float px = xin[p * 3 + 0];
            const float py = xin[p * 3 + 1];
            const float pz = xin[p * 3 + 2];
            const float pxs = px * 31.5f + 31.5f;
            const float pys = py * 31.5f + 31.5f;
            const float pzs = pz * 31.5f + 31.5f;

            int   xoS[4][3], yoS[4][3], zoS[4][3], zdS[4][3];
            float wxS[4][3], wyS[4][3], wzS[4][3];
#pragma unroll
            for (int q = 0; q < 4; ++q) {
                const float sc31 = (float)(2 << q) * (31.5f / 64.0f);
#pragma unroll
                for (int pos = 0; pos < 3; ++pos) {
                    const float gv = (-2.0f + 1.5f * (float)pos) * sc31;
                    {
                        float ix = fminf(fmaxf(pxs + gv, 0.f), 63.f);
                        float xf = floorf(ix); int x0 = (int)xf; float fx = ix - xf;
                        int x1 = min(x0 + 1, 63);
                        xoS[q][pos] = ((cxb ? x1 : x0) << XS) + pr * PRB;
                        wxS[q][pos] = cxb ? fx : 1.f - fx;
                    }
                    {
                        float iy = fminf(fmaxf(pys + gv, 0.f), 63.f);
                        float yf = floorf(iy); int y0 = (int)yf; float fy = iy - yf;
                        int y1 = min(y0 + 1, 63);
                        yoS[q][pos] = (cyb ? y1 : y0) << YS;
                        wyS[q][pos] = cyb ? fy : 1.f - fy;
                    }
                    {
                        float iz = fminf(fmaxf(pzs + gv, 0.f), 63.f);
                        float zf = floorf(iz); int z0 = (int)zf; float fz = iz - zf;
                        int z1 = min(z0 + 1, 63);
                        zoS[q][pos] = (z0 << ZS) + (q << QS);
                        zdS[q][pos] = (z1 - z0) << ZS;
                        wzS[q][pos] = fz;
                    }
                }
            }

#pragma unroll
            for (int j = 0; j < 3; ++j)
#pragma unroll
            for (int i = 0; i < 3; ++i) {
                int   yxo[4];
                float wyx[4];
#pragma unroll
                for (int q = 0; q < 4; ++q) {
                    yxo[q] = yoS[q][i] + xoS[q][j];
                    wyx[q] = wyS[q][i] * wxS[q][j];
                }
#pragma unroll
                for (int k = 0; k < 3; ++k) {
                    f32x2 acc = {0.f, 0.f};
#pragma unroll
                    for (int q = 0; q < 4; ++q) {
                        const int a0 = zoS[q][k] + yxo[q];
                        const int a1 = a0 + zdS[q][k];
                        f32x2 r0, r1;
                        if (VT16) {
                            const unsigned u0 = llvm_amdgcn_raw_buffer_load_u32(srsrc, a0, 0, 0);
                            const unsigned u1 = llvm_amdgcn_raw_buffer_load_u32(srsrc, a1, 0, 0);
                            r0.x = __uint_as_float(u0 << 16);
                            r0.y = __uint_as_float(u0 & 0xffff0000u);
                            r1.x = __uint_as_float(u1 << 16);
                            r1.y = __uint_as_float(u1 & 0xffff0000u);
                        } else {
                            r0 = *(const f32x2*)(vtb + a0);
                            r1 = *(const f32x2*)(vtb + a1);
                        }
                        const float fz = wzS[q][k];
                        const f32x2 fz2  = {fz, fz};
                        const f32x2 wyx2 = {wyx[q], wyx[q]};
                        const f32x2 t = r0 + (r1 - r0) * fz2;   // z-lerp
                        acc = acc + t * wyx2;
                    }
                    float ax = acc.x, ay = acc.y;
                    ax += __shfl_xor(ax, 16); ax += __shfl_xor(ax, 32);
                    ay += __shfl_xor(ay, 16); ay += __shfl_xor(ay, 32);
                    if (lane < 16) {
                        unsigned u;
                        asm("v_cvt_pk_bf16_f32 %0, %1, %2" : "=v"(u) : "v"(ax), "v"(ay));
                        ((unsigned*)&rowA[pt][0])[(j * 9 + i * 3 + k) * 16 + pr] = u;
                    }
                }
            }
        }
    }

    // ---- fc1: z_point -> zcat[:,0:128]; 32 pts x 32 groups x 4 outs ----
    {
        const int ptp = tid >> 5;       // 0..31
        const int og  = tid & 31;
        const int sp  = min(p0 + ptp, m - 1);
        const int p   = SORT ? perm[sp] : sp;
        const float qx = xin[p * 3 + 0], qy = xin[p * 3 + 1], qz = xin[p * 3 + 2];
#pragma unroll
        for (int r = 0; r < 4; ++r) {
            const int o = og + 32 * r;
            float v = qx * fc1w[o * 3 + 0] + qy * fc1w[o * 3 + 1] + qz * fc1w[o * 3 + 2] + fc1b[o];
            v = fmaxf(v, 0.2f * v);
            zcat[ptp][o] = __float2bfloat16(v);
        }
    }
    __syncthreads();

    // ---- conv [32x864]x[864x64]: waves 0..7 = (wr:2 rows) x (wc:4 cols); A from LDS ----
    if (wave < 8) {
        const int wc = wave & 3, wr = wave >> 2;
        f32x4 acc = {0.f, 0.f, 0.f, 0.f};
#pragma unroll
        for (int ks = 0; ks < 27; ++ks) {
            short8 af = *(const short8*)&rowA[wr * 16 + row][ks * 32 + g * 8];
            short8 bf = *(const short8*)(w0f + (((size_t)wc * 27 + ks) * 64 + lane) * 8);
            acc = __builtin_amdgcn_mfma_f32_16x16x32_bf16(af, bf, acc, 0, 0, 0);
        }
        const int o = wc * 16 + row;
        const float bias = b0[o];
#pragma unroll
        for (int r = 0; r < 4; ++r)
            z0l[wr * 16 + g * 4 + r][o] = __float2bfloat16(acc[r] + bias);
    }
    __syncthreads();

    // ---- lfc [32x64]x[64x128]: 16 tiles (tr = wave>>3, tc = wave&7) ----
    {
        const int tr = wave >> 3, tc = wave & 7;
        f32x4 acc = {0.f, 0.f, 0.f, 0.f};
#pragma unroll
        for (int ks = 0; ks < 2; ++ks) {
            short8 af = *(const short8*)&z0l[tr * 16 + row][ks * 32 + g * 8];
            short8 bf = *(const short8*)(w1f + (((size_t)tc * 2 + ks) * 64 + lane) * 8);
            acc = __builtin_amdgcn_mfma_f32_16x16x32_bf16(af, bf, acc, 0, 0, 0);
        }
        const int o = tc * 16 + row;
        const float bias = b1[o];
#pragma unroll
        for (int r = 0; r < 4; ++r)
            zcat[tr * 16 + g * 4 + r][128 + o] = __float2bfloat16(acc[r] + bias);
    }
    __syncthreads();

    // ---- fc2 [32x256]x[256x512]: wave -> tc in {2w, 2w+1}, both row-tiles; B reused x2 ----
    {
        f32x4 acc[2][2];
#pragma unroll
        for (int c = 0; c < 2; ++c)
#pragma unroll
            for (int t = 0; t < 2; ++t) acc[c][t] = (f32x4){0.f, 0.f, 0.f, 0.f};
#pragma unroll
        for (int ks = 0; ks < 8; ++ks) {
            short8 a0 = *(const short8*)&zcat[row][ks * 32 + g * 8];
            short8 a1 = *(const short8*)&zcat[16 + row][ks * 32 + g * 8];
#pragma unroll
            for (int c = 0; c < 2; ++c) {
                short8 bf = *(const short8*)(w2f + (((size_t)(wave * 2 + c) * 8 + ks) * 64 + lane) * 8);
                acc[c][0] = __builtin_amdgcn_mfma_f32_16x16x32_bf16(a0, bf, acc[c][0], 0, 0, 0);
                acc[c][1] = __builtin_amdgcn_mfma_f32_16x16x32_bf16(a1, bf, acc[c][1], 0, 0, 0);
            }
        }
        __syncthreads();   // rowA (= z2l region) reads fully done before overwrite
#pragma unroll
        for (int c = 0; c < 2; ++c) {
            const int o = (wave * 2 + c) * 16 + row;
            const float bias = b2[o];
#pragma unroll
            for (int r = 0; r < 4; ++r) {
                float v0 = acc[c][0][r] + bias; v0 = fmaxf(v0, 0.2f * v0);
                float v1 = acc[c][1][r] + bias; v1 = fmaxf(v1, 0.2f * v1);
                z2l[g * 4 + r][o]      = __float2bfloat16(v0);
                z2l[16 + g * 4 + r][o] = __float2bfloat16(v1);
            }
        }
    }
    __syncthreads();

    // ---- fc3 [32x512]x[512x256]: wave -> tc = wave, both row-tiles ----
    {
        f32x4 acc0 = {0.f, 0.f, 0.f, 0.f}, acc1 = {0.f, 0.f, 0.f, 0.f};
#pragma unroll
        for (int ks = 0; ks < 16; ++ks) {
            short8 a0 = *(const short8*)&z2l[row][ks * 32 + g * 8];
            short8 a1 = *(const short8*)&z2l[16 + row][ks * 32 + g * 8];
            short8 bf = *(const short8*)(w3f + (((size_t)wave * 16 + ks) * 64 + lane) * 8);
            acc0 = __builtin_amdgcn_mfma_f32_16x16x32_bf16(a0, bf, acc0, 0, 0, 0);
            acc1 = __builtin_amdgcn_mfma_f32_16x16x32_bf16(a1, bf, acc1, 0, 0, 0);
        }
        const int o = wave * 16 + row;
        const float bias = b3[o];
#pragma unroll
        for (int r = 0; r < 4; ++r) {
            float v0 = acc0[r] + bias; v0 = fmaxf(v0, 0.2f * v0);
            float v1 = acc1[r] + bias; v1 = fmaxf(v1, 0.2f * v1);
            z3l[g * 4 + r][o]      = __float2bfloat16(v0);
            z3l[16 + g * 4 + r][o] = __float2bfloat16(v1);
        }
    }
    __syncthreads();

    // ---- fc4 [32x256]x[256x16(pad)]: waves 0..1 (tr = wave), 8 MFMA each ----
    if (wave < 2) {
        f32x4 acc = {0.f, 0.f, 0.f, 0.f};
#pragma unroll
        for (int ks = 0; ks < 8; ++ks) {
            short8 af = *(const short8*)&z3l[wave * 16 + row][ks * 32 + g * 8];
            short8 bf = *(const short8*)(w4f + (((size_t)ks) * 64 + lane) * 8);
            acc = __builtin_amdgcn_mfma_f32_16x16x32_bf16(af, bf, acc, 0, 0, 0);
        }
        const int o = row;   // D col = output channel (0..2 valid)
        if (o < 3) {
            const float bias = fc4b[o];
#pragma unroll
            for (int r = 0; r < 4; ++r) {
                const int spg = p0 + wave * 16 + g * 4 + r;
                if (spg < m) {
                    const int pg = SORT ? perm[spg] : spg;
                    out[pg * 3 + o] = acc[r] + bias;
                }
            }
        }
    }
}

extern "C" void kernel_launch(void* const* d_in, const int* in_sizes, int n_in,
                              void* d_out, int out_size, void* d_ws, size_t ws_size,
                              hipStream_t stream) {
    const float* x      = (const float*)d_in[1];
    const float* v0     = (const float*)d_in[2];
    const float* v1     = (const float*)d_in[3];
    const float* v2     = (const float*)d_in[4];
    const float* v3     = (const float*)d_in[5];
    const float* conv_w = (const float*)d_in[6];
    const float* conv_b = (const float*)d_in[7];
    const float* lfc_w  = (const float*)d_in[8];
    const float* lfc_b  = (const float*)d_in[9];
    const float* fc1_w  = (const float*)d_in[10];
    const float* fc1_b  = (const float*)d_in[11];
    const float* fc2_w  = (const float*)d_in[12];
    const float* fc2_b  = (const float*)d_in[13];
    const float* fc3_w  = (const float*)d_in[14];
    const float* fc3_b  = (const float*)d_in[15];
    const float* fc4_w  = (const float*)d_in[16];
    const float* fc4_b  = (const float*)d_in[17];
    float* out = (float*)d_out;
    const int m = in_sizes[1] / 3;

    char* ws = (char*)d_ws;
    size_t woff = 0;
    __hip_bfloat16* w0f = (__hip_bfloat16*)(ws + woff); woff += (size_t)55296 * 2;
    __hip_bfloat16* w1f = (__hip_bfloat16*)(ws + woff); woff += (size_t)8192 * 2;
    __hip_bfloat16* w2f = (__hip_bfloat16*)(ws + woff); woff += (size_t)131072 * 2;
    __hip_bfloat16* w3f = (__hip_bfloat16*)(ws + woff); woff += (size_t)131072 * 2;
    __hip_bfloat16* w4f = (__hip_bfloat16*)(ws + woff); woff += (size_t)4096 * 2;
    woff = (woff + 255) & ~(size_t)255;
    int* hist   = (int*)(ws + woff); woff += NCELL * 4;
    int* cursor = (int*)(ws + woff); woff += NCELL * 4;
    int* perm   = (int*)(ws + woff); woff += ((size_t)m * 4 + 255) & ~(size_t)255;

    const size_t vt32_bytes = (size_t)4 * VOXELS * 32 * 4;   // 128 MiB
    const size_t vt16_bytes = (size_t)4 * VOXELS * 32 * 2;   // 64 MiB

    const size_t need16 = woff + vt16_bytes;
    const size_t need32 = woff + vt32_bytes;

    k_prepw_all<<<(329728 + 255) / 256, 256, 0, stream>>>(conv_w, lfc_w, fc2_w, fc3_w, fc4_w,
                                                          w0f, w1f, w2f, w3f, w4f);

    const int nb  = (m + 31) / 32;
    const int npb = (m + 255) / 256;

    if (ws_size >= need16) {
        void* vt = (void*)(ws + woff);
        hipMemsetAsync(hist, 0, NCELL * 4, stream);
        k_hist<<<npb, 256, 0, stream>>>(x, hist, m);
        k_scan<<<1, 64, 0, stream>>>(hist, cursor);
        k_scatter<<<npb, 256, 0, stream>>>(x, cursor, perm, m);
        if (ws_size >= need32) {
            // fp32 channel-last variant unused by default; bf16 preferred (r7/r8 A/B)
        }
        k_transpose<true><<<16384, 256, 0, stream>>>(v0, v1, v2, v3, vt);
        k_all<true, true><<<nb, 1024, 0, stream>>>(x, vt, perm, w0f, conv_b, w1f, lfc_b,
                                                   fc1_w, fc1_b, w2f, fc2_b, w3f, fc3_b,
                                                   w4f, fc4_b, out, m, nb);
    } else {
        // minimal fallback (never expected: ws has been >=216 MB every round):
        // no sort, bf16 vt cannot fit -> sample from fp32 channel-last needs 128 MB;
        // if even that fails, run unsorted bf16-vt path anyway using whatever ws has.
        void* vt = (void*)(ws + woff);
        k_transpose<true><<<16384, 256, 0, stream>>>(v0, v1, v2, v3, vt);
        k_all<true, false><<<nb, 1024, 0, stream>>>(x, vt, nullptr, w0f, conv_b, w1f, lfc_b,
                                                    fc1_w, fc1_b, w2f, fc2_b, w3f, fc3_b,
                                                    w4f, fc4_b, out, m, nb);
    }
}

// Round 13
// 750.415 us; speedup vs baseline: 1.1104x; 1.1104x over previous
//
#include <hip/hip_runtime.h>
#include <hip/hip_bf16.h>

typedef __attribute__((ext_vector_type(8))) short short8;
typedef __attribute__((ext_vector_type(4))) float f32x4;
typedef __attribute__((ext_vector_type(2))) float f32x2;
typedef __attribute__((ext_vector_type(4))) int int32x4;

// raw buffer load: 32-bit voffset addressing (no per-lane 64-bit addr VALU).
__device__ unsigned int llvm_amdgcn_raw_buffer_load_u32(int32x4 srsrc, int voffset,
                                                        int soffset, int aux)
    __asm("llvm.amdgcn.raw.buffer.load.i32");

#define VOXELS 262144  // 64^3
#define ZC_PAD 264
#define Z0_PAD 72
#define Z2_PAD 520
#define Z3_PAD 264
#define NCELL  512     // 8x8x8 Morton cells

// ---------------- volume transpose: (C,D,H,W) -> (D,H,W,C) ----------------
template <bool VT16>
__global__ void k_transpose(const float* __restrict__ v0, const float* __restrict__ v1,
                            const float* __restrict__ v2, const float* __restrict__ v3,
                            void* __restrict__ vtp) {
    int b  = blockIdx.x;
    int q  = b >> 12;
    int zy = b & 4095;
    const float* src = (q == 0) ? v0 : (q == 1) ? v1 : (q == 2) ? v2 : v3;
    __shared__ float buf[32][65];
    int t = threadIdx.x;
    int x = t & 63, c0 = t >> 6;
    for (int cp = 0; cp < 32; cp += 4) {
        int c = c0 + cp;
        buf[c][x] = src[(size_t)c * VOXELS + (size_t)zy * 64 + x];
    }
    __syncthreads();
    int c = t & 31, xg = t >> 5;
    const size_t base = ((size_t)q * VOXELS + (size_t)zy * 64) * 32;
    for (int xx = xg; xx < 64; xx += 8) {
        if (VT16) ((__hip_bfloat16*)vtp)[base + xx * 32 + c] = __float2bfloat16(buf[c][xx]);
        else      ((float*)vtp)[base + xx * 32 + c] = buf[c][xx];
    }
}

// ------------- merged weight pack: all 5 weight tensors in ONE launch -------------
__device__ __forceinline__ void prep_one(const float* __restrict__ W,
                                         __hip_bfloat16* __restrict__ wf,
                                         int K, int mode, int n) {
    int e = n & 7, lane = (n >> 3) & 63;
    int rest = n >> 9;
    int ksteps = K >> 5;
    int kstep = rest % ksteps, otile = rest / ksteps;
    int o = otile * 16 + (lane & 15);
    int k = kstep * 32 + (lane >> 4) * 8 + e;
    float v;
    if (mode == 1)      v = W[(size_t)o * K + (k & 31) * 27 + (k >> 5)];
    else if (mode == 2) v = (o < 3) ? W[(size_t)o * K + k] : 0.f;
    else                v = W[(size_t)o * K + k];
    wf[n] = __float2bfloat16(v);
}

__global__ void k_prepw_all(const float* __restrict__ conv_w, const float* __restrict__ lfc_w,
                            const float* __restrict__ fc2_w, const float* __restrict__ fc3_w,
                            const float* __restrict__ fc4_w,
                            __hip_bfloat16* __restrict__ w0f, __hip_bfloat16* __restrict__ w1f,
                            __hip_bfloat16* __restrict__ w2f, __hip_bfloat16* __restrict__ w3f,
                            __hip_bfloat16* __restrict__ w4f) {
    int n = blockIdx.x * blockDim.x + threadIdx.x;
    if (n < 55296)                prep_one(conv_w, w0f, 864, 1, n);
    else if (n < 63488)           prep_one(lfc_w,  w1f, 64,  0, n - 55296);
    else if (n < 194560)          prep_one(fc2_w,  w2f, 256, 0, n - 63488);
    else if (n < 325632)          prep_one(fc3_w,  w3f, 512, 0, n - 194560);
    else if (n < 329728)          prep_one(fc4_w,  w4f, 256, 2, n - 325632);
}

// ================= spatial sort (counting sort by Morton cell) =================
__device__ __forceinline__ int point_cell(float px, float py, float pz) {
    int cx = min(63, max(0, (int)(px * 31.5f + 31.5f))) >> 3;
    int cy = min(63, max(0, (int)(py * 31.5f + 31.5f))) >> 3;
    int cz = min(63, max(0, (int)(pz * 31.5f + 31.5f))) >> 3;
    int k = 0;
#pragma unroll
    for (int b = 0; b < 3; ++b)
        k |= (((cx >> b) & 1) << (3 * b)) | (((cy >> b) & 1) << (3 * b + 1))
           | (((cz >> b) & 1) << (3 * b + 2));
    return k;
}

__global__ void k_hist(const float* __restrict__ xin, int* __restrict__ hist, int m) {
    int p = blockIdx.x * blockDim.x + threadIdx.x;
    if (p >= m) return;
    atomicAdd(&hist[point_cell(xin[p * 3], xin[p * 3 + 1], xin[p * 3 + 2])], 1);
}

// single-wave exclusive scan of 512 cells
__global__ __launch_bounds__(64)
void k_scan(const int* __restrict__ hist, int* __restrict__ cursor) {
    const int t = threadIdx.x;   // 0..63
    int vals[8];
    int s = 0;
#pragma unroll
    for (int k = 0; k < 8; ++k) { vals[k] = hist[t * 8 + k]; s += vals[k]; }
    int pre = s;
#pragma unroll
    for (int off = 1; off < 64; off <<= 1) {
        int u = __shfl_up(pre, off);
        if (t >= off) pre += u;
    }
    int run = pre - s;   // exclusive prefix of this lane's first cell
#pragma unroll
    for (int k = 0; k < 8; ++k) { cursor[t * 8 + k] = run; run += vals[k]; }
}

__global__ void k_scatter(const float* __restrict__ xin, int* __restrict__ cursor,
                          int* __restrict__ perm, int m) {
    int p = blockIdx.x * blockDim.x + threadIdx.x;
    if (p >= m) return;
    int cell = point_cell(xin[p * 3], xin[p * 3 + 1], xin[p * 3 + 2]);
    int pos = atomicAdd(&cursor[cell], 1);
    perm[pos] = p;
}

// ============ standalone sampler: 1 point/wave, 4 waves/block ============
// r13: __launch_bounds__(256, 8) — r11 ran at 41% occupancy with VGPR=56 and
// nothing else capping residency; the (256,4) bound only requested 4 waves/EU.
// Cap 64 VGPR >= the 56 in use, so no spill (canary: WRITE_SIZE stays ~86 MB).
// r12's full fusion spilled (VGPR forced to 32, 504 MB scratch) — reverted.
template <bool VT16, bool SORT>
__global__ __launch_bounds__(256, 8)
void k_sample(const float* __restrict__ xin, const void* __restrict__ vtp,
              const int* __restrict__ perm,
              __hip_bfloat16* __restrict__ fbuf, int m, int nblk) {
    __shared__ __align__(16) __hip_bfloat16 rowbuf[4][896];  // 864 + pad

    // bijective XCD swizzle: contiguous chunk of sorted points per XCD
    int b = blockIdx.x;
    {
        const int qd = nblk >> 3, r = nblk & 7;
        const int xcd = b & 7, i = b >> 3;
        b = (xcd < r) ? xcd * (qd + 1) + i : r * (qd + 1) + (xcd - r) * qd + i;
    }
    const int lane = threadIdx.x & 63;
    const int wv   = threadIdx.x >> 6;
    const int sp = b * 4 + wv;
    if (sp >= m) return;
    const int p = SORT ? perm[sp] : sp;

    const float px = xin[p * 3 + 0];
    const float py = xin[p * 3 + 1];
    const float pz = xin[p * 3 + 2];

    const int pr  = lane & 15;         // channel pair
    const int cxb = (lane >> 4) & 1;   // x corner
    const int cyb = (lane >> 5) & 1;   // y corner

    const float pxs = px * 31.5f + 31.5f;
    const float pys = py * 31.5f + 31.5f;
    const float pzs = pz * 31.5f + 31.5f;

    const int XS  = VT16 ? 6 : 7;
    const int YS  = VT16 ? 12 : 13;
    const int ZS  = VT16 ? 18 : 19;
    const int QS  = VT16 ? 24 : 25;
    const int PRB = VT16 ? 4 : 8;      // bytes per channel pair

    int   xoS[4][3], yoS[4][3], zoS[4][3], zdS[4][3];
    float wxS[4][3], wyS[4][3], wzS[4][3];
#pragma unroll
    for (int q = 0; q < 4; ++q) {
        const float sc31 = (float)(2 << q) * (31.5f / 64.0f);
#pragma unroll
        for (int pos = 0; pos < 3; ++pos) {
            const float gv = (-2.0f + 1.5f * (float)pos) * sc31;  // compile-time
            {
                float ix = fminf(fmaxf(pxs + gv, 0.f), 63.f);
                float xf = floorf(ix); int x0 = (int)xf; float fx = ix - xf;
                int x1 = min(x0 + 1, 63);
                xoS[q][pos] = ((cxb ? x1 : x0) << XS) + pr * PRB;
                wxS[q][pos] = cxb ? fx : 1.f - fx;
            }
            {
                float iy = fminf(fmaxf(pys + gv, 0.f), 63.f);
                float yf = floorf(iy); int y0 = (int)yf; float fy = iy - yf;
                int y1 = min(y0 + 1, 63);
                yoS[q][pos] = (cyb ? y1 : y0) << YS;
                wyS[q][pos] = cyb ? fy : 1.f - fy;
            }
            {
                float iz = fminf(fmaxf(pzs + gv, 0.f), 63.f);
                float zf = floorf(iz); int z0 = (int)zf; float fz = iz - zf;
                int z1 = min(z0 + 1, 63);
                zoS[q][pos] = (z0 << ZS) + (q << QS);
                zdS[q][pos] = (z1 - z0) << ZS;
                wzS[q][pos] = fz;   // weight of z1 corner
            }
        }
    }

    // SRSRC for vt (wave-uniform base; per-lane 32-bit voffset)
    int32x4 srsrc;
    srsrc.x = (int)(unsigned)(uintptr_t)vtp;
    srsrc.y = (int)((uintptr_t)vtp >> 32);
    srsrc.z = -1;                            // bounds check off
    srsrc.w = 0x00020000;                    // raw dword access

    const char* __restrict__ vtb = (const char*)vtp;
#pragma unroll
    for (int j = 0; j < 3; ++j)
#pragma unroll
    for (int i = 0; i < 3; ++i) {
        int   yxo[4];
        float wyx[4];
#pragma unroll
        for (int q = 0; q < 4; ++q) {
            yxo[q] = yoS[q][i] + xoS[q][j];
            wyx[q] = wyS[q][i] * wxS[q][j];
        }
#pragma unroll
        for (int k = 0; k < 3; ++k) {
            f32x2 acc = {0.f, 0.f};
#pragma unroll
            for (int q = 0; q < 4; ++q) {
                const int a0 = zoS[q][k] + yxo[q];
                const int a1 = a0 + zdS[q][k];
                f32x2 r0, r1;
                if (VT16) {
                    const unsigned u0 = llvm_amdgcn_raw_buffer_load_u32(srsrc, a0, 0, 0);
                    const unsigned u1 = llvm_amdgcn_raw_buffer_load_u32(srsrc, a1, 0, 0);
                    r0.x = __uint_as_float(u0 << 16);
                    r0.y = __uint_as_float(u0 & 0xffff0000u);
                    r1.x = __uint_as_float(u1 << 16);
                    r1.y = __uint_as_float(u1 & 0xffff0000u);
                } else {
                    r0 = *(const f32x2*)(vtb + a0);
                    r1 = *(const f32x2*)(vtb + a1);
                }
                const float fz = wzS[q][k];
                const f32x2 fz2  = {fz, fz};
                const f32x2 wyx2 = {wyx[q], wyx[q]};
                const f32x2 t = r0 + (r1 - r0) * fz2;   // z-lerp
                acc = acc + t * wyx2;
            }
            float ax = acc.x, ay = acc.y;
            ax += __shfl_xor(ax, 16); ax += __shfl_xor(ax, 32);
            ay += __shfl_xor(ay, 16); ay += __shfl_xor(ay, 32);
            if (lane < 16) {
                unsigned u;
                asm("v_cvt_pk_bf16_f32 %0, %1, %2" : "=v"(u) : "v"(ax), "v"(ay));
                ((unsigned*)&rowbuf[wv][0])[(j * 9 + i * 3 + k) * 16 + pr] = u;
            }
        }
    }

    // dense row write, NON-TEMPORAL (r7: fixed 10x write-amp + L2 thrash)
    {
        const f32x4* __restrict__ lsrc = (const f32x4*)&rowbuf[wv][0];
        f32x4* __restrict__ gdst = (f32x4*)(fbuf + (size_t)sp * 864);
#pragma unroll
        for (int r = 0; r < 2; ++r) {
            const int idx = r * 64 + lane;
            if (idx < 108) __builtin_nontemporal_store(lsrc[idx], &gdst[idx]);
        }
    }
}

// ============ MLP kernel v4: 32 points/block, 512 threads, 8 waves (r11) ============
template <bool SORT>
__global__ __launch_bounds__(512, 4)
void k_mlp(const float* __restrict__ xin, const __hip_bfloat16* __restrict__ fbuf,
           const int* __restrict__ perm,
           const __hip_bfloat16* __restrict__ w0f, const float* __restrict__ b0,
           const __hip_bfloat16* __restrict__ w1f, const float* __restrict__ b1,
           const float* __restrict__ fc1w, const float* __restrict__ fc1b,
           const __hip_bfloat16* __restrict__ w2f, const float* __restrict__ b2,
           const __hip_bfloat16* __restrict__ w3f, const float* __restrict__ b3,
           const __hip_bfloat16* __restrict__ w4f, const float* __restrict__ fc4b,
           float* __restrict__ out, int m) {
    __shared__ __align__(16) __hip_bfloat16 zcat[32][ZC_PAD];   // 16.9 KB
    __shared__ __align__(16) __hip_bfloat16 z0l[32][Z0_PAD];    //  4.6 KB
    __shared__ __align__(16) char shr[32 * 1744];               // 55.8 KB union
    __hip_bfloat16 (*rowA)[872]  = (__hip_bfloat16(*)[872])shr;            // stage+conv
    __hip_bfloat16 (*z2l)[Z2_PAD] = (__hip_bfloat16(*)[Z2_PAD])shr;        // fc2+
    __hip_bfloat16 (*z3l)[Z3_PAD] = (__hip_bfloat16(*)[Z3_PAD])(shr + 33280);

    const int tid  = threadIdx.x;
    const int wave = tid >> 6;     // 0..7
    const int lane = tid & 63;
    const int p0   = blockIdx.x * 32;
    const int row  = lane & 15, g = lane >> 4;

    // ---- stage 32 fbuf rows -> rowA (padded stride 872; 2-way bank alias) ----
    {
        const int rrow = (wave << 2) + (lane >> 4);   // 0..31
        const int srow = min(p0 + rrow, m - 1);
        const f32x4* __restrict__ src = (const f32x4*)(fbuf + (size_t)srow * 864);
        const int c16 = lane & 15;
#pragma unroll
        for (int k = 0; k < 7; ++k) {
            const int chunk = c16 + k * 16;
            if (chunk < 108)
                *(f32x4*)&rowA[rrow][chunk * 8] = src[chunk];
        }
    }

    // ---- fc1: z_point -> zcat[:,0:128] ----
    {
        const int ptp = tid >> 4;       // 0..31
        const int og  = tid & 15;
        const int sp  = min(p0 + ptp, m - 1);
        const int p   = SORT ? perm[sp] : sp;
        const float qx = xin[p * 3 + 0], qy = xin[p * 3 + 1], qz = xin[p * 3 + 2];
#pragma unroll
        for (int r = 0; r < 8; ++r) {
            const int o = og * 8 + r;
            float v = qx * fc1w[o * 3 + 0] + qy * fc1w[o * 3 + 1] + qz * fc1w[o * 3 + 2] + fc1b[o];
            v = fmaxf(v, 0.2f * v);
            zcat[ptp][o] = __float2bfloat16(v);
        }
    }
    __syncthreads();

    // ---- conv [32x864]x[864x64]: wave = (wr:2 rows) x (wc:4 cols); A from LDS ----
    {
        const int wc = wave & 3, wr = wave >> 2;
        f32x4 acc = {0.f, 0.f, 0.f, 0.f};
#pragma unroll
        for (int ks = 0; ks < 27; ++ks) {
            short8 af = *(const short8*)&rowA[wr * 16 + row][ks * 32 + g * 8];
            short8 bf = *(const short8*)(w0f + (((size_t)wc * 27 + ks) * 64 + lane) * 8);
            acc = __builtin_amdgcn_mfma_f32_16x16x32_bf16(af, bf, acc, 0, 0, 0);
        }
        const int o = wc * 16 + row;
        const float bias = b0[o];
#pragma unroll
        for (int r = 0; r < 4; ++r)
            z0l[wr * 16 + g * 4 + r][o] = __float2bfloat16(acc[r] + bias);
    }
    __syncthreads();

    // ---- lfc [32x64]x[64x128]: tc = wave; B reused across 2 row-tiles ----
    {
        const int tc = wave;
        f32x4 acc0 = {0.f, 0.f, 0.f, 0.f}, acc1 = {0.f, 0.f, 0.f, 0.f};
#pragma unroll
        for (int ks = 0; ks < 2; ++ks) {
            short8 bf = *(const short8*)(w1f + (((size_t)tc * 2 + ks) * 64 + lane) * 8);
            short8 a0 = *(const short8*)&z0l[row][ks * 32 + g * 8];
            short8 a1 = *(const short8*)&z0l[16 + row][ks * 32 + g * 8];
            acc0 = __builtin_amdgcn_mfma_f32_16x16x32_bf16(a0, bf, acc0, 0, 0, 0);
            acc1 = __builtin_amdgcn_mfma_f32_16x16x32_bf16(a1, bf, acc1, 0, 0, 0);
        }
        const int o = tc * 16 + row;
        const float bias = b1[o];
#pragma unroll
        for (int r = 0; r < 4; ++r) {
            zcat[g * 4 + r][128 + o]      = __float2bfloat16(acc0[r] + bias);
            zcat[16 + g * 4 + r][128 + o] = __float2bfloat16(acc1[r] + bias);
        }
    }
    __syncthreads();

    // ---- fc2 [32x256]x[256x512]: tc = wave*4+c; A loaded once per (ks,tr) ----
    {
        f32x4 acc[4][2];
#pragma unroll
        for (int c = 0; c < 4; ++c)
#pragma unroll
            for (int t = 0; t < 2; ++t) acc[c][t] = (f32x4){0.f, 0.f, 0.f, 0.f};
#pragma unroll
        for (int ks = 0; ks < 8; ++ks) {
            short8 a0 = *(const short8*)&zcat[row][ks * 32 + g * 8];
            short8 a1 = *(const short8*)&zcat[16 + row][ks * 32 + g * 8];
#pragma unroll
            for (int c = 0; c < 4; ++c) {
                short8 bf = *(const short8*)(w2f + (((size_t)(wave * 4 + c) * 8 + ks) * 64 + lane) * 8);
                acc[c][0] = __builtin_amdgcn_mfma_f32_16x16x32_bf16(a0, bf, acc[c][0], 0, 0, 0);
                acc[c][1] = __builtin_amdgcn_mfma_f32_16x16x32_bf16(a1, bf, acc[c][1], 0, 0, 0);
            }
        }
#pragma unroll
        for (int c = 0; c < 4; ++c) {
            const int o = (wave * 4 + c) * 16 + row;
            const float bias = b2[o];
#pragma unroll
            for (int r = 0; r < 4; ++r) {
                float v0 = acc[c][0][r] + bias; v0 = fmaxf(v0, 0.2f * v0);
                float v1 = acc[c][1][r] + bias; v1 = fmaxf(v1, 0.2f * v1);
                z2l[g * 4 + r][o]      = __float2bfloat16(v0);
                z2l[16 + g * 4 + r][o] = __float2bfloat16(v1);
            }
        }
    }
    __syncthreads();

    // ---- fc3 [32x512]x[512x256]: tc = wave*2+c ----
    {
        f32x4 acc[2][2];
#pragma unroll
        for (int c = 0; c < 2; ++c)
#pragma unroll
            for (int t = 0; t < 2; ++t) acc[c][t] = (f32x4){0.f, 0.f, 0.f, 0.f};
#pragma unroll
        for (int ks = 0; ks < 16; ++ks) {
            short8 a0 = *(const short8*)&z2l[row][ks * 32 + g * 8];
            short8 a1 = *(const short8*)&z2l[16 + row][ks * 32 + g * 8];
#pragma unroll
            for (int c = 0; c < 2; ++c) {
                short8 bf = *(const short8*)(w3f + (((size_t)(wave * 2 + c) * 16 + ks) * 64 + lane) * 8);
                acc[c][0] = __builtin_amdgcn_mfma_f32_16x16x32_bf16(a0, bf, acc[c][0], 0, 0, 0);
                acc[c][1] = __builtin_amdgcn_mfma_f32_16x16x32_bf16(a1, bf, acc[c][1], 0, 0, 0);
            }
        }
#pragma unroll
        for (int c = 0; c < 2; ++c) {
            const int o = (wave * 2 + c) * 16 + row;
            const float bias = b3[o];
#pragma unroll
            for (int r = 0; r < 4; ++r) {
                float v0 = acc[c][0][r] + bias; v0 = fmaxf(v0, 0.2f * v0);
                float v1 = acc[c][1][r] + bias; v1 = fmaxf(v1, 0.2f * v1);
                z3l[g * 4 + r][o]      = __float2bfloat16(v0);
                z3l[16 + g * 4 + r][o] = __float2bfloat16(v1);
            }
        }
    }
    __syncthreads();

    // ---- fc4 [32x256]x[256x16(pad)]: waves 0..1 (tr = wave), 8 MFMA each ----
    if (wave < 2) {
        f32x4 acc = {0.f, 0.f, 0.f, 0.f};
#pragma unroll
        for (int ks = 0; ks < 8; ++ks) {
            short8 af = *(const short8*)&z3l[wave * 16 + row][ks * 32 + g * 8];
            short8 bf = *(const short8*)(w4f + (((size_t)ks) * 64 + lane) * 8);
            acc = __builtin_amdgcn_mfma_f32_16x16x32_bf16(af, bf, acc, 0, 0, 0);
        }
        const int o = row;
        if (o < 3) {
            const float bias = fc4b[o];
#pragma unroll
            for (int r = 0; r < 4; ++r) {
                const int spg = p0 + wave * 16 + g * 4 + r;
                if (spg < m) {
                    const int pg = SORT ? perm[spg] : spg;
                    out[pg * 3 + o] = acc[r] + bias;
                }
            }
        }
    }
}

extern "C" void kernel_launch(void* const* d_in, const int* in_sizes, int n_in,
                              void* d_out, int out_size, void* d_ws, size_t ws_size,
                              hipStream_t stream) {
    const float* x      = (const float*)d_in[1];
    const float* v0     = (const float*)d_in[2];
    const float* v1     = (const float*)d_in[3];
    const float* v2     = (const float*)d_in[4];
    const float* v3     = (const float*)d_in[5];
    const float* conv_w = (const float*)d_in[6];
    const float* conv_b = (const float*)d_in[7];
    const float* lfc_w  = (const float*)d_in[8];
    const float* lfc_b  = (const float*)d_in[9];
    const float* fc1_w  = (const float*)d_in[10];
    const float* fc1_b  = (const float*)d_in[11];
    const float* fc2_w  = (const float*)d_in[12];
    const float* fc2_b  = (const float*)d_in[13];
    const float* fc3_w  = (const float*)d_in[14];
    const float* fc3_b  = (const float*)d_in[15];
    const float* fc4_w  = (const float*)d_in[16];
    const float* fc4_b  = (const float*)d_in[17];
    float* out = (float*)d_out;
    const int m = in_sizes[1] / 3;

    char* ws = (char*)d_ws;
    size_t woff = 0;
    __hip_bfloat16* w0f = (__hip_bfloat16*)(ws + woff); woff += (size_t)55296 * 2;
    __hip_bfloat16* w1f = (__hip_bfloat16*)(ws + woff); woff += (size_t)8192 * 2;
    __hip_bfloat16* w2f = (__hip_bfloat16*)(ws + woff); woff += (size_t)131072 * 2;
    __hip_bfloat16* w3f = (__hip_bfloat16*)(ws + woff); woff += (size_t)131072 * 2;
    __hip_bfloat16* w4f = (__hip_bfloat16*)(ws + woff); woff += (size_t)4096 * 2;
    woff = (woff + 255) & ~(size_t)255;
    int* hist   = (int*)(ws + woff); woff += NCELL * 4;
    int* cursor = (int*)(ws + woff); woff += NCELL * 4;
    int* perm   = (int*)(ws + woff); woff += ((size_t)m * 4 + 255) & ~(size_t)255;

    const size_t vt32_bytes = (size_t)4 * VOXELS * 32 * 4;   // 128 MiB
    const size_t vt16_bytes = (size_t)4 * VOXELS * 32 * 2;   // 64 MiB
    const size_t fbytes     = ((size_t)m * 864 * 2 + 255) & ~(size_t)255;

    const size_t need_split16 = woff + vt16_bytes + fbytes;
    const size_t need_split32 = woff + vt32_bytes + fbytes;

    k_prepw_all<<<(329728 + 255) / 256, 256, 0, stream>>>(conv_w, lfc_w, fc2_w, fc3_w, fc4_w,
                                                          w0f, w1f, w2f, w3f, w4f);

    const int nsb = (m + 3) / 4;
    const int nb  = (m + 31) / 32;
    const int npb = (m + 255) / 256;

    if (ws_size >= need_split16) {
        // ---- preferred: bf16 channel-last vt + Morton sort ----
        void* vt = (void*)(ws + woff);
        __hip_bfloat16* fbuf = (__hip_bfloat16*)(ws + woff + vt16_bytes);
        hipMemsetAsync(hist, 0, NCELL * 4, stream);
        k_hist<<<npb, 256, 0, stream>>>(x, hist, m);
        k_scan<<<1, 64, 0, stream>>>(hist, cursor);
        k_scatter<<<npb, 256, 0, stream>>>(x, cursor, perm, m);
        k_transpose<true><<<16384, 256, 0, stream>>>(v0, v1, v2, v3, vt);
        k_sample<true, true><<<nsb, 256, 0, stream>>>(x, vt, perm, fbuf, m, nsb);
        k_mlp<true><<<nb, 512, 0, stream>>>(x, fbuf, perm, w0f, conv_b, w1f, lfc_b,
                                            fc1_w, fc1_b, w2f, fc2_b, w3f, fc3_b,
                                            w4f, fc4_b, out, m);
    } else if (ws_size >= need_split32) {
        void* vt = (void*)(ws + woff);
        __hip_bfloat16* fbuf = (__hip_bfloat16*)(ws + woff + vt32_bytes);
        hipMemsetAsync(hist, 0, NCELL * 4, stream);
        k_hist<<<npb, 256, 0, stream>>>(x, hist, m);
        k_scan<<<1, 64, 0, stream>>>(hist, cursor);
        k_scatter<<<npb, 256, 0, stream>>>(x, cursor, perm, m);
        k_transpose<false><<<16384, 256, 0, stream>>>(v0, v1, v2, v3, vt);
        k_sample<false, true><<<nsb, 256, 0, stream>>>(x, vt, perm, fbuf, m, nsb);
        k_mlp<true><<<nb, 512, 0, stream>>>(x, fbuf, perm, w0f, conv_b, w1f, lfc_b,
                                            fc1_w, fc1_b, w2f, fc2_b, w3f, fc3_b,
                                            w4f, fc4_b, out, m);
    } else {
        __hip_bfloat16* fbuf = (__hip_bfloat16*)(ws + woff);
        k_sample<false, false><<<nsb, 256, 0, stream>>>(x, nullptr, perm, fbuf, m, nsb);
        k_mlp<false><<<nb, 512, 0, stream>>>(x, fbuf, perm, w0f, conv_b, w1f, lfc_b,
                                             fc1_w, fc1_b, w2f, fc2_b, w3f, fc3_b,
                                             w4f, fc4_b, out, m);
    }
}

// Round 14
// 631.379 us; speedup vs baseline: 1.3197x; 1.1885x over previous
//
#include <hip/hip_runtime.h>
#include <hip/hip_bf16.h>

typedef __attribute__((ext_vector_type(8))) short short8;
typedef __attribute__((ext_vector_type(4))) float f32x4;
typedef __attribute__((ext_vector_type(2))) float f32x2;
typedef __attribute__((ext_vector_type(4))) int int32x4;

// raw buffer load: 32-bit voffset addressing (no per-lane 64-bit addr VALU).
__device__ unsigned int llvm_amdgcn_raw_buffer_load_u32(int32x4 srsrc, int voffset,
                                                        int soffset, int aux)
    __asm("llvm.amdgcn.raw.buffer.load.i32");

#define VOXELS 262144  // 64^3
#define ZC_PAD 264
#define Z0_PAD 72
#define Z2_PAD 520
#define Z3_PAD 264
#define NCELL  512     // 8x8x8 Morton cells

// ---------------- volume transpose: (C,D,H,W) -> (D,H,W,C) ----------------
template <bool VT16>
__global__ void k_transpose(const float* __restrict__ v0, const float* __restrict__ v1,
                            const float* __restrict__ v2, const float* __restrict__ v3,
                            void* __restrict__ vtp) {
    int b  = blockIdx.x;
    int q  = b >> 12;
    int zy = b & 4095;
    const float* src = (q == 0) ? v0 : (q == 1) ? v1 : (q == 2) ? v2 : v3;
    __shared__ float buf[32][65];
    int t = threadIdx.x;
    int x = t & 63, c0 = t >> 6;
    for (int cp = 0; cp < 32; cp += 4) {
        int c = c0 + cp;
        buf[c][x] = src[(size_t)c * VOXELS + (size_t)zy * 64 + x];
    }
    __syncthreads();
    int c = t & 31, xg = t >> 5;
    const size_t base = ((size_t)q * VOXELS + (size_t)zy * 64) * 32;
    for (int xx = xg; xx < 64; xx += 8) {
        if (VT16) ((__hip_bfloat16*)vtp)[base + xx * 32 + c] = __float2bfloat16(buf[c][xx]);
        else      ((float*)vtp)[base + xx * 32 + c] = buf[c][xx];
    }
}

// ------------- merged weight pack: all 5 weight tensors in ONE launch -------------
__device__ __forceinline__ void prep_one(const float* __restrict__ W,
                                         __hip_bfloat16* __restrict__ wf,
                                         int K, int mode, int n) {
    int e = n & 7, lane = (n >> 3) & 63;
    int rest = n >> 9;
    int ksteps = K >> 5;
    int kstep = rest % ksteps, otile = rest / ksteps;
    int o = otile * 16 + (lane & 15);
    int k = kstep * 32 + (lane >> 4) * 8 + e;
    float v;
    if (mode == 1)      v = W[(size_t)o * K + (k & 31) * 27 + (k >> 5)];
    else if (mode == 2) v = (o < 3) ? W[(size_t)o * K + k] : 0.f;
    else                v = W[(size_t)o * K + k];
    wf[n] = __float2bfloat16(v);
}

__global__ void k_prepw_all(const float* __restrict__ conv_w, const float* __restrict__ lfc_w,
                            const float* __restrict__ fc2_w, const float* __restrict__ fc3_w,
                            const float* __restrict__ fc4_w,
                            __hip_bfloat16* __restrict__ w0f, __hip_bfloat16* __restrict__ w1f,
                            __hip_bfloat16* __restrict__ w2f, __hip_bfloat16* __restrict__ w3f,
                            __hip_bfloat16* __restrict__ w4f) {
    int n = blockIdx.x * blockDim.x + threadIdx.x;
    if (n < 55296)                prep_one(conv_w, w0f, 864, 1, n);
    else if (n < 63488)           prep_one(lfc_w,  w1f, 64,  0, n - 55296);
    else if (n < 194560)          prep_one(fc2_w,  w2f, 256, 0, n - 63488);
    else if (n < 325632)          prep_one(fc3_w,  w3f, 512, 0, n - 194560);
    else if (n < 329728)          prep_one(fc4_w,  w4f, 256, 2, n - 325632);
}

// ================= spatial sort (counting sort by Morton cell) =================
__device__ __forceinline__ int point_cell(float px, float py, float pz) {
    int cx = min(63, max(0, (int)(px * 31.5f + 31.5f))) >> 3;
    int cy = min(63, max(0, (int)(py * 31.5f + 31.5f))) >> 3;
    int cz = min(63, max(0, (int)(pz * 31.5f + 31.5f))) >> 3;
    int k = 0;
#pragma unroll
    for (int b = 0; b < 3; ++b)
        k |= (((cx >> b) & 1) << (3 * b)) | (((cy >> b) & 1) << (3 * b + 1))
           | (((cz >> b) & 1) << (3 * b + 2));
    return k;
}

__global__ void k_hist(const float* __restrict__ xin, int* __restrict__ hist, int m) {
    int p = blockIdx.x * blockDim.x + threadIdx.x;
    if (p >= m) return;
    atomicAdd(&hist[point_cell(xin[p * 3], xin[p * 3 + 1], xin[p * 3 + 2])], 1);
}

// single-wave exclusive scan of 512 cells
__global__ __launch_bounds__(64)
void k_scan(const int* __restrict__ hist, int* __restrict__ cursor) {
    const int t = threadIdx.x;   // 0..63
    int vals[8];
    int s = 0;
#pragma unroll
    for (int k = 0; k < 8; ++k) { vals[k] = hist[t * 8 + k]; s += vals[k]; }
    int pre = s;
#pragma unroll
    for (int off = 1; off < 64; off <<= 1) {
        int u = __shfl_up(pre, off);
        if (t >= off) pre += u;
    }
    int run = pre - s;   // exclusive prefix of this lane's first cell
#pragma unroll
    for (int k = 0; k < 8; ++k) { cursor[t * 8 + k] = run; run += vals[k]; }
}

__global__ void k_scatter(const float* __restrict__ xin, int* __restrict__ cursor,
                          int* __restrict__ perm, int m) {
    int p = blockIdx.x * blockDim.x + threadIdx.x;
    if (p >= m) return;
    int cell = point_cell(xin[p * 3], xin[p * 3 + 1], xin[p * 3 + 2]);
    int pos = atomicAdd(&cursor[cell], 1);
    perm[pos] = p;
}

// ============ standalone sampler: 1 point/wave, 4 waves/block ============
// r14: back to the r11 body. Launch bounds (256,6): VGPR cap ~85 >> 56 in
// use, so the allocator has no shrink pressure (r12/r13 lesson: asking for
// >=8 waves/EU makes the compiler clamp VGPR to 32 and SPILL — 0.5 GB of
// scratch writes; canary = VGPR_Count < 50 or WRITE_SIZE >> 86 MB).
template <bool VT16, bool SORT>
__global__ __launch_bounds__(256, 6)
void k_sample(const float* __restrict__ xin, const void* __restrict__ vtp,
              const int* __restrict__ perm,
              __hip_bfloat16* __restrict__ fbuf, int m, int nblk) {
    __shared__ __align__(16) __hip_bfloat16 rowbuf[4][896];  // 864 + pad

    // bijective XCD swizzle: contiguous chunk of sorted points per XCD
    int b = blockIdx.x;
    {
        const int qd = nblk >> 3, r = nblk & 7;
        const int xcd = b & 7, i = b >> 3;
        b = (xcd < r) ? xcd * (qd + 1) + i : r * (qd + 1) + (xcd - r) * qd + i;
    }
    const int lane = threadIdx.x & 63;
    const int wv   = threadIdx.x >> 6;
    const int sp = b * 4 + wv;
    if (sp >= m) return;
    const int p = SORT ? perm[sp] : sp;

    const float px = xin[p * 3 + 0];
    const float py = xin[p * 3 + 1];
    const float pz = xin[p * 3 + 2];

    const int pr  = lane & 15;         // channel pair
    const int cxb = (lane >> 4) & 1;   // x corner
    const int cyb = (lane >> 5) & 1;   // y corner

    const float pxs = px * 31.5f + 31.5f;
    const float pys = py * 31.5f + 31.5f;
    const float pzs = pz * 31.5f + 31.5f;

    const int XS  = VT16 ? 6 : 7;
    const int YS  = VT16 ? 12 : 13;
    const int ZS  = VT16 ? 18 : 19;
    const int QS  = VT16 ? 24 : 25;
    const int PRB = VT16 ? 4 : 8;      // bytes per channel pair

    int   xoS[4][3], yoS[4][3], zoS[4][3], zdS[4][3];
    float wxS[4][3], wyS[4][3], wzS[4][3];
#pragma unroll
    for (int q = 0; q < 4; ++q) {
        const float sc31 = (float)(2 << q) * (31.5f / 64.0f);
#pragma unroll
        for (int pos = 0; pos < 3; ++pos) {
            const float gv = (-2.0f + 1.5f * (float)pos) * sc31;  // compile-time
            {
                float ix = fminf(fmaxf(pxs + gv, 0.f), 63.f);
                float xf = floorf(ix); int x0 = (int)xf; float fx = ix - xf;
                int x1 = min(x0 + 1, 63);
                xoS[q][pos] = ((cxb ? x1 : x0) << XS) + pr * PRB;
                wxS[q][pos] = cxb ? fx : 1.f - fx;
            }
            {
                float iy = fminf(fmaxf(pys + gv, 0.f), 63.f);
                float yf = floorf(iy); int y0 = (int)yf; float fy = iy - yf;
                int y1 = min(y0 + 1, 63);
                yoS[q][pos] = (cyb ? y1 : y0) << YS;
                wyS[q][pos] = cyb ? fy : 1.f - fy;
            }
            {
                float iz = fminf(fmaxf(pzs + gv, 0.f), 63.f);
                float zf = floorf(iz); int z0 = (int)zf; float fz = iz - zf;
                int z1 = min(z0 + 1, 63);
                zoS[q][pos] = (z0 << ZS) + (q << QS);
                zdS[q][pos] = (z1 - z0) << ZS;
                wzS[q][pos] = fz;   // weight of z1 corner
            }
        }
    }

    // SRSRC for vt (wave-uniform base; per-lane 32-bit voffset)
    int32x4 srsrc;
    srsrc.x = (int)(unsigned)(uintptr_t)vtp;
    srsrc.y = (int)((uintptr_t)vtp >> 32);
    srsrc.z = -1;                            // bounds check off
    srsrc.w = 0x00020000;                    // raw dword access

    const char* __restrict__ vtb = (const char*)vtp;
#pragma unroll
    for (int j = 0; j < 3; ++j)
#pragma unroll
    for (int i = 0; i < 3; ++i) {
        int   yxo[4];
        float wyx[4];
#pragma unroll
        for (int q = 0; q < 4; ++q) {
            yxo[q] = yoS[q][i] + xoS[q][j];
            wyx[q] = wyS[q][i] * wxS[q][j];
        }
#pragma unroll
        for (int k = 0; k < 3; ++k) {
            f32x2 acc = {0.f, 0.f};
#pragma unroll
            for (int q = 0; q < 4; ++q) {
                const int a0 = zoS[q][k] + yxo[q];
                const int a1 = a0 + zdS[q][k];
                f32x2 r0, r1;
                if (VT16) {
                    const unsigned u0 = llvm_amdgcn_raw_buffer_load_u32(srsrc, a0, 0, 0);
                    const unsigned u1 = llvm_amdgcn_raw_buffer_load_u32(srsrc, a1, 0, 0);
                    r0.x = __uint_as_float(u0 << 16);
                    r0.y = __uint_as_float(u0 & 0xffff0000u);
                    r1.x = __uint_as_float(u1 << 16);
                    r1.y = __uint_as_float(u1 & 0xffff0000u);
                } else {
                    r0 = *(const f32x2*)(vtb + a0);
                    r1 = *(const f32x2*)(vtb + a1);
                }
                const float fz = wzS[q][k];
                const f32x2 fz2  = {fz, fz};
                const f32x2 wyx2 = {wyx[q], wyx[q]};
                const f32x2 t = r0 + (r1 - r0) * fz2;   // z-lerp
                acc = acc + t * wyx2;
            }
            float ax = acc.x, ay = acc.y;
            ax += __shfl_xor(ax, 16); ax += __shfl_xor(ax, 32);
            ay += __shfl_xor(ay, 16); ay += __shfl_xor(ay, 32);
            if (lane < 16) {
                unsigned u;
                asm("v_cvt_pk_bf16_f32 %0, %1, %2" : "=v"(u) : "v"(ax), "v"(ay));
                ((unsigned*)&rowbuf[wv][0])[(j * 9 + i * 3 + k) * 16 + pr] = u;
            }
        }
    }

    // dense row write, NON-TEMPORAL (r7: fixed 10x write-amp + L2 thrash)
    {
        const f32x4* __restrict__ lsrc = (const f32x4*)&rowbuf[wv][0];
        f32x4* __restrict__ gdst = (f32x4*)(fbuf + (size_t)sp * 864);
#pragma unroll
        for (int r = 0; r < 2; ++r) {
            const int idx = r * 64 + lane;
            if (idx < 108) __builtin_nontemporal_store(lsrc[idx], &gdst[idx]);
        }
    }
}

// ============ MLP kernel v4: 32 points/block, 512 threads, 8 waves (r11) ============
template <bool SORT>
__global__ __launch_bounds__(512, 4)
void k_mlp(const float* __restrict__ xin, const __hip_bfloat16* __restrict__ fbuf,
           const int* __restrict__ perm,
           const __hip_bfloat16* __restrict__ w0f, const float* __restrict__ b0,
           const __hip_bfloat16* __restrict__ w1f, const float* __restrict__ b1,
           const float* __restrict__ fc1w, const float* __restrict__ fc1b,
           const __hip_bfloat16* __restrict__ w2f, const float* __restrict__ b2,
           const __hip_bfloat16* __restrict__ w3f, const float* __restrict__ b3,
           const __hip_bfloat16* __restrict__ w4f, const float* __restrict__ fc4b,
           float* __restrict__ out, int m) {
    __shared__ __align__(16) __hip_bfloat16 zcat[32][ZC_PAD];   // 16.9 KB
    __shared__ __align__(16) __hip_bfloat16 z0l[32][Z0_PAD];    //  4.6 KB
    __shared__ __align__(16) char shr[32 * 1744];               // 55.8 KB union
    __hip_bfloat16 (*rowA)[872]  = (__hip_bfloat16(*)[872])shr;            // stage+conv
    __hip_bfloat16 (*z2l)[Z2_PAD] = (__hip_bfloat16(*)[Z2_PAD])shr;        // fc2+
    __hip_bfloat16 (*z3l)[Z3_PAD] = (__hip_bfloat16(*)[Z3_PAD])(shr + 33280);

    const int tid  = threadIdx.x;
    const int wave = tid >> 6;     // 0..7
    const int lane = tid & 63;
    const int p0   = blockIdx.x * 32;
    const int row  = lane & 15, g = lane >> 4;

    // ---- stage 32 fbuf rows -> rowA (padded stride 872; 2-way bank alias) ----
    {
        const int rrow = (wave << 2) + (lane >> 4);   // 0..31
        const int srow = min(p0 + rrow, m - 1);
        const f32x4* __restrict__ src = (const f32x4*)(fbuf + (size_t)srow * 864);
        const int c16 = lane & 15;
#pragma unroll
        for (int k = 0; k < 7; ++k) {
            const int chunk = c16 + k * 16;
            if (chunk < 108)
                *(f32x4*)&rowA[rrow][chunk * 8] = src[chunk];
        }
    }

    // ---- fc1: z_point -> zcat[:,0:128] ----
    {
        const int ptp = tid >> 4;       // 0..31
        const int og  = tid & 15;
        const int sp  = min(p0 + ptp, m - 1);
        const int p   = SORT ? perm[sp] : sp;
        const float qx = xin[p * 3 + 0], qy = xin[p * 3 + 1], qz = xin[p * 3 + 2];
#pragma unroll
        for (int r = 0; r < 8; ++r) {
            const int o = og * 8 + r;
            float v = qx * fc1w[o * 3 + 0] + qy * fc1w[o * 3 + 1] + qz * fc1w[o * 3 + 2] + fc1b[o];
            v = fmaxf(v, 0.2f * v);
            zcat[ptp][o] = __float2bfloat16(v);
        }
    }
    __syncthreads();

    // ---- conv [32x864]x[864x64]: wave = (wr:2 rows) x (wc:4 cols); A from LDS ----
    {
        const int wc = wave & 3, wr = wave >> 2;
        f32x4 acc = {0.f, 0.f, 0.f, 0.f};
#pragma unroll
        for (int ks = 0; ks < 27; ++ks) {
            short8 af = *(const short8*)&rowA[wr * 16 + row][ks * 32 + g * 8];
            short8 bf = *(const short8*)(w0f + (((size_t)wc * 27 + ks) * 64 + lane) * 8);
            acc = __builtin_amdgcn_mfma_f32_16x16x32_bf16(af, bf, acc, 0, 0, 0);
        }
        const int o = wc * 16 + row;
        const float bias = b0[o];
#pragma unroll
        for (int r = 0; r < 4; ++r)
            z0l[wr * 16 + g * 4 + r][o] = __float2bfloat16(acc[r] + bias);
    }
    __syncthreads();

    // ---- lfc [32x64]x[64x128]: tc = wave; B reused across 2 row-tiles ----
    {
        const int tc = wave;
        f32x4 acc0 = {0.f, 0.f, 0.f, 0.f}, acc1 = {0.f, 0.f, 0.f, 0.f};
#pragma unroll
        for (int ks = 0; ks < 2; ++ks) {
            short8 bf = *(const short8*)(w1f + (((size_t)tc * 2 + ks) * 64 + lane) * 8);
            short8 a0 = *(const short8*)&z0l[row][ks * 32 + g * 8];
            short8 a1 = *(const short8*)&z0l[16 + row][ks * 32 + g * 8];
            acc0 = __builtin_amdgcn_mfma_f32_16x16x32_bf16(a0, bf, acc0, 0, 0, 0);
            acc1 = __builtin_amdgcn_mfma_f32_16x16x32_bf16(a1, bf, acc1, 0, 0, 0);
        }
        const int o = tc * 16 + row;
        const float bias = b1[o];
#pragma unroll
        for (int r = 0; r < 4; ++r) {
            zcat[g * 4 + r][128 + o]      = __float2bfloat16(acc0[r] + bias);
            zcat[16 + g * 4 + r][128 + o] = __float2bfloat16(acc1[r] + bias);
        }
    }
    __syncthreads();

    // ---- fc2 [32x256]x[256x512]: tc = wave*4+c; A loaded once per (ks,tr) ----
    {
        f32x4 acc[4][2];
#pragma unroll
        for (int c = 0; c < 4; ++c)
#pragma unroll
            for (int t = 0; t < 2; ++t) acc[c][t] = (f32x4){0.f, 0.f, 0.f, 0.f};
#pragma unroll
        for (int ks = 0; ks < 8; ++ks) {
            short8 a0 = *(const short8*)&zcat[row][ks * 32 + g * 8];
            short8 a1 = *(const short8*)&zcat[16 + row][ks * 32 + g * 8];
#pragma unroll
            for (int c = 0; c < 4; ++c) {
                short8 bf = *(const short8*)(w2f + (((size_t)(wave * 4 + c) * 8 + ks) * 64 + lane) * 8);
                acc[c][0] = __builtin_amdgcn_mfma_f32_16x16x32_bf16(a0, bf, acc[c][0], 0, 0, 0);
                acc[c][1] = __builtin_amdgcn_mfma_f32_16x16x32_bf16(a1, bf, acc[c][1], 0, 0, 0);
            }
        }
#pragma unroll
        for (int c = 0; c < 4; ++c) {
            const int o = (wave * 4 + c) * 16 + row;
            const float bias = b2[o];
#pragma unroll
            for (int r = 0; r < 4; ++r) {
                float v0 = acc[c][0][r] + bias; v0 = fmaxf(v0, 0.2f * v0);
                float v1 = acc[c][1][r] + bias; v1 = fmaxf(v1, 0.2f * v1);
                z2l[g * 4 + r][o]      = __float2bfloat16(v0);
                z2l[16 + g * 4 + r][o] = __float2bfloat16(v1);
            }
        }
    }
    __syncthreads();

    // ---- fc3 [32x512]x[512x256]: tc = wave*2+c ----
    {
        f32x4 acc[2][2];
#pragma unroll
        for (int c = 0; c < 2; ++c)
#pragma unroll
            for (int t = 0; t < 2; ++t) acc[c][t] = (f32x4){0.f, 0.f, 0.f, 0.f};
#pragma unroll
        for (int ks = 0; ks < 16; ++ks) {
            short8 a0 = *(const short8*)&z2l[row][ks * 32 + g * 8];
            short8 a1 = *(const short8*)&z2l[16 + row][ks * 32 + g * 8];
#pragma unroll
            for (int c = 0; c < 2; ++c) {
                short8 bf = *(const short8*)(w3f + (((size_t)(wave * 2 + c) * 16 + ks) * 64 + lane) * 8);
                acc[c][0] = __builtin_amdgcn_mfma_f32_16x16x32_bf16(a0, bf, acc[c][0], 0, 0, 0);
                acc[c][1] = __builtin_amdgcn_mfma_f32_16x16x32_bf16(a1, bf, acc[c][1], 0, 0, 0);
            }
        }
#pragma unroll
        for (int c = 0; c < 2; ++c) {
            const int o = (wave * 2 + c) * 16 + row;
            const float bias = b3[o];
#pragma unroll
            for (int r = 0; r < 4; ++r) {
                float v0 = acc[c][0][r] + bias; v0 = fmaxf(v0, 0.2f * v0);
                float v1 = acc[c][1][r] + bias; v1 = fmaxf(v1, 0.2f * v1);
                z3l[g * 4 + r][o]      = __float2bfloat16(v0);
                z3l[16 + g * 4 + r][o] = __float2bfloat16(v1);
            }
        }
    }
    __syncthreads();

    // ---- fc4 [32x256]x[256x16(pad)]: waves 0..1 (tr = wave), 8 MFMA each ----
    if (wave < 2) {
        f32x4 acc = {0.f, 0.f, 0.f, 0.f};
#pragma unroll
        for (int ks = 0; ks < 8; ++ks) {
            short8 af = *(const short8*)&z3l[wave * 16 + row][ks * 32 + g * 8];
            short8 bf = *(const short8*)(w4f + (((size_t)ks) * 64 + lane) * 8);
            acc = __builtin_amdgcn_mfma_f32_16x16x32_bf16(af, bf, acc, 0, 0, 0);
        }
        const int o = row;
        if (o < 3) {
            const float bias = fc4b[o];
#pragma unroll
            for (int r = 0; r < 4; ++r) {
                const int spg = p0 + wave * 16 + g * 4 + r;
                if (spg < m) {
                    const int pg = SORT ? perm[spg] : spg;
                    out[pg * 3 + o] = acc[r] + bias;
                }
            }
        }
    }
}

extern "C" void kernel_launch(void* const* d_in, const int* in_sizes, int n_in,
                              void* d_out, int out_size, void* d_ws, size_t ws_size,
                              hipStream_t stream) {
    const float* x      = (const float*)d_in[1];
    const float* v0     = (const float*)d_in[2];
    const float* v1     = (const float*)d_in[3];
    const float* v2     = (const float*)d_in[4];
    const float* v3     = (const float*)d_in[5];
    const float* conv_w = (const float*)d_in[6];
    const float* conv_b = (const float*)d_in[7];
    const float* lfc_w  = (const float*)d_in[8];
    const float* lfc_b  = (const float*)d_in[9];
    const float* fc1_w  = (const float*)d_in[10];
    const float* fc1_b  = (const float*)d_in[11];
    const float* fc2_w  = (const float*)d_in[12];
    const float* fc2_b  = (const float*)d_in[13];
    const float* fc3_w  = (const float*)d_in[14];
    const float* fc3_b  = (const float*)d_in[15];
    const float* fc4_w  = (const float*)d_in[16];
    const float* fc4_b  = (const float*)d_in[17];
    float* out = (float*)d_out;
    const int m = in_sizes[1] / 3;

    char* ws = (char*)d_ws;
    size_t woff = 0;
    __hip_bfloat16* w0f = (__hip_bfloat16*)(ws + woff); woff += (size_t)55296 * 2;
    __hip_bfloat16* w1f = (__hip_bfloat16*)(ws + woff); woff += (size_t)8192 * 2;
    __hip_bfloat16* w2f = (__hip_bfloat16*)(ws + woff); woff += (size_t)131072 * 2;
    __hip_bfloat16* w3f = (__hip_bfloat16*)(ws + woff); woff += (size_t)131072 * 2;
    __hip_bfloat16* w4f = (__hip_bfloat16*)(ws + woff); woff += (size_t)4096 * 2;
    woff = (woff + 255) & ~(size_t)255;
    int* hist   = (int*)(ws + woff); woff += NCELL * 4;
    int* cursor = (int*)(ws + woff); woff += NCELL * 4;
    int* perm   = (int*)(ws + woff); woff += ((size_t)m * 4 + 255) & ~(size_t)255;

    const size_t vt32_bytes = (size_t)4 * VOXELS * 32 * 4;   // 128 MiB
    const size_t vt16_bytes = (size_t)4 * VOXELS * 32 * 2;   // 64 MiB
    const size_t fbytes     = ((size_t)m * 864 * 2 + 255) & ~(size_t)255;

    const size_t need_split16 = woff + vt16_bytes + fbytes;
    const size_t need_split32 = woff + vt32_bytes + fbytes;

    k_prepw_all<<<(329728 + 255) / 256, 256, 0, stream>>>(conv_w, lfc_w, fc2_w, fc3_w, fc4_w,
                                                          w0f, w1f, w2f, w3f, w4f);

    const int nsb = (m + 3) / 4;
    const int nb  = (m + 31) / 32;
    const int npb = (m + 255) / 256;

    if (ws_size >= need_split16) {
        // ---- preferred: bf16 channel-last vt + Morton sort ----
        void* vt = (void*)(ws + woff);
        __hip_bfloat16* fbuf = (__hip_bfloat16*)(ws + woff + vt16_bytes);
        hipMemsetAsync(hist, 0, NCELL * 4, stream);
        k_hist<<<npb, 256, 0, stream>>>(x, hist, m);
        k_scan<<<1, 64, 0, stream>>>(hist, cursor);
        k_scatter<<<npb, 256, 0, stream>>>(x, cursor, perm, m);
        k_transpose<true><<<16384, 256, 0, stream>>>(v0, v1, v2, v3, vt);
        k_sample<true, true><<<nsb, 256, 0, stream>>>(x, vt, perm, fbuf, m, nsb);
        k_mlp<true><<<nb, 512, 0, stream>>>(x, fbuf, perm, w0f, conv_b, w1f, lfc_b,
                                            fc1_w, fc1_b, w2f, fc2_b, w3f, fc3_b,
                                            w4f, fc4_b, out, m);
    } else if (ws_size >= need_split32) {
        void* vt = (void*)(ws + woff);
        __hip_bfloat16* fbuf = (__hip_bfloat16*)(ws + woff + vt32_bytes);
        hipMemsetAsync(hist, 0, NCELL * 4, stream);
        k_hist<<<npb, 256, 0, stream>>>(x, hist, m);
        k_scan<<<1, 64, 0, stream>>>(hist, cursor);
        k_scatter<<<npb, 256, 0, stream>>>(x, cursor, perm, m);
        k_transpose<false><<<16384, 256, 0, stream>>>(v0, v1, v2, v3, vt);
        k_sample<false, true><<<nsb, 256, 0, stream>>>(x, vt, perm, fbuf, m, nsb);
        k_mlp<true><<<nb, 512, 0, stream>>>(x, fbuf, perm, w0f, conv_b, w1f, lfc_b,
                                            fc1_w, fc1_b, w2f, fc2_b, w3f, fc3_b,
                                            w4f, fc4_b, out, m);
    } else {
        __hip_bfloat16* fbuf = (__hip_bfloat16*)(ws + woff);
        k_sample<false, false><<<nsb, 256, 0, stream>>>(x, nullptr, perm, fbuf, m, nsb);
        k_mlp<false><<<nb, 512, 0, stream>>>(x, fbuf, perm, w0f, conv_b, w1f, lfc_b,
                                             fc1_w, fc1_b, w2f, fc2_b, w3f, fc3_b,
                                             w4f, fc4_b, out, m);
    }
}

// Round 15
// 405.491 us; speedup vs baseline: 2.0549x; 1.5571x over previous
//
#include <hip/hip_runtime.h>
#include <hip/hip_bf16.h>

typedef __attribute__((ext_vector_type(8))) short short8;
typedef __attribute__((ext_vector_type(4))) float f32x4;
typedef __attribute__((ext_vector_type(2))) float f32x2;
typedef __attribute__((ext_vector_type(4))) int int32x4;

// raw buffer load: 32-bit voffset addressing (no per-lane 64-bit addr VALU).
__device__ unsigned int llvm_amdgcn_raw_buffer_load_u32(int32x4 srsrc, int voffset,
                                                        int soffset, int aux)
    __asm("llvm.amdgcn.raw.buffer.load.i32");

#define VOXELS 262144  // 64^3
#define ZC_PAD 264
#define Z0_PAD 72
#define Z2_PAD 520
#define Z3_PAD 264
#define NCELL  512     // 8x8x8 Morton cells

// ---------------- volume transpose: (C,D,H,W) -> (D,H,W,C) ----------------
template <bool VT16>
__global__ void k_transpose(const float* __restrict__ v0, const float* __restrict__ v1,
                            const float* __restrict__ v2, const float* __restrict__ v3,
                            void* __restrict__ vtp) {
    int b  = blockIdx.x;
    int q  = b >> 12;
    int zy = b & 4095;
    const float* src = (q == 0) ? v0 : (q == 1) ? v1 : (q == 2) ? v2 : v3;
    __shared__ float buf[32][65];
    int t = threadIdx.x;
    int x = t & 63, c0 = t >> 6;
    for (int cp = 0; cp < 32; cp += 4) {
        int c = c0 + cp;
        buf[c][x] = src[(size_t)c * VOXELS + (size_t)zy * 64 + x];
    }
    __syncthreads();
    const size_t base = ((size_t)q * VOXELS + (size_t)zy * 64) * 32;
    if (VT16) {
        // r15: dword stores (2 bf16 channels/thread) -> 256 B contiguous per wave instr
        const int cp2 = t & 15;       // channel pair
        const int xg  = t >> 4;       // 16 x-positions per pass
        unsigned* dstw = (unsigned*)((__hip_bfloat16*)vtp + base);
        for (int xx = xg; xx < 64; xx += 16) {
            __hip_bfloat16 h0 = __float2bfloat16(buf[cp2 * 2][xx]);
            __hip_bfloat16 h1 = __float2bfloat16(buf[cp2 * 2 + 1][xx]);
            unsigned u = ((unsigned)*(unsigned short*)&h1 << 16) | *(unsigned short*)&h0;
            dstw[xx * 16 + cp2] = u;
        }
    } else {
        int c = t & 31, xg = t >> 5;
        for (int xx = xg; xx < 64; xx += 8) {
            ((float*)vtp)[base + xx * 32 + c] = buf[c][xx];
        }
    }
}

// ------------- merged weight pack: all 5 weight tensors in ONE launch -------------
__device__ __forceinline__ void prep_one(const float* __restrict__ W,
                                         __hip_bfloat16* __restrict__ wf,
                                         int K, int mode, int n) {
    int e = n & 7, lane = (n >> 3) & 63;
    int rest = n >> 9;
    int ksteps = K >> 5;
    int kstep = rest % ksteps, otile = rest / ksteps;
    int o = otile * 16 + (lane & 15);
    int k = kstep * 32 + (lane >> 4) * 8 + e;
    float v;
    if (mode == 1)      v = W[(size_t)o * K + (k & 31) * 27 + (k >> 5)];
    else if (mode == 2) v = (o < 3) ? W[(size_t)o * K + k] : 0.f;
    else                v = W[(size_t)o * K + k];
    wf[n] = __float2bfloat16(v);
}

__global__ void k_prepw_all(const float* __restrict__ conv_w, const float* __restrict__ lfc_w,
                            const float* __restrict__ fc2_w, const float* __restrict__ fc3_w,
                            const float* __restrict__ fc4_w,
                            __hip_bfloat16* __restrict__ w0f, __hip_bfloat16* __restrict__ w1f,
                            __hip_bfloat16* __restrict__ w2f, __hip_bfloat16* __restrict__ w3f,
                            __hip_bfloat16* __restrict__ w4f) {
    int n = blockIdx.x * blockDim.x + threadIdx.x;
    if (n < 55296)                prep_one(conv_w, w0f, 864, 1, n);
    else if (n < 63488)           prep_one(lfc_w,  w1f, 64,  0, n - 55296);
    else if (n < 194560)          prep_one(fc2_w,  w2f, 256, 0, n - 63488);
    else if (n < 325632)          prep_one(fc3_w,  w3f, 512, 0, n - 194560);
    else if (n < 329728)          prep_one(fc4_w,  w4f, 256, 2, n - 325632);
}

// ================= spatial sort (counting sort by Morton cell) =================
__device__ __forceinline__ int point_cell(float px, float py, float pz) {
    int cx = min(63, max(0, (int)(px * 31.5f + 31.5f))) >> 3;
    int cy = min(63, max(0, (int)(py * 31.5f + 31.5f))) >> 3;
    int cz = min(63, max(0, (int)(pz * 31.5f + 31.5f))) >> 3;
    int k = 0;
#pragma unroll
    for (int b = 0; b < 3; ++b)
        k |= (((cx >> b) & 1) << (3 * b)) | (((cy >> b) & 1) << (3 * b + 1))
           | (((cz >> b) & 1) << (3 * b + 2));
    return k;
}

__global__ void k_hist(const float* __restrict__ xin, int* __restrict__ hist, int m) {
    int p = blockIdx.x * blockDim.x + threadIdx.x;
    if (p >= m) return;
    atomicAdd(&hist[point_cell(xin[p * 3], xin[p * 3 + 1], xin[p * 3 + 2])], 1);
}

// single-wave exclusive scan of 512 cells
__global__ __launch_bounds__(64)
void k_scan(const int* __restrict__ hist, int* __restrict__ cursor) {
    const int t = threadIdx.x;   // 0..63
    int vals[8];
    int s = 0;
#pragma unroll
    for (int k = 0; k < 8; ++k) { vals[k] = hist[t * 8 + k]; s += vals[k]; }
    int pre = s;
#pragma unroll
    for (int off = 1; off < 64; off <<= 1) {
        int u = __shfl_up(pre, off);
        if (t >= off) pre += u;
    }
    int run = pre - s;   // exclusive prefix of this lane's first cell
#pragma unroll
    for (int k = 0; k < 8; ++k) { cursor[t * 8 + k] = run; run += vals[k]; }
}

__global__ void k_scatter(const float* __restrict__ xin, int* __restrict__ cursor,
                          int* __restrict__ perm, int m) {
    int p = blockIdx.x * blockDim.x + threadIdx.x;
    if (p >= m) return;
    int cell = point_cell(xin[p * 3], xin[p * 3 + 1], xin[p * 3 + 2]);
    int pos = atomicAdd(&cursor[cell], 1);
    perm[pos] = p;
}

// ============ standalone sampler: 1 point/wave, 4 waves/block ============
// r15: zoS/zdS/wzS are WAVE-UNIFORM (z axis has no lane dependence) — force
// them to SGPRs via readfirstlane, freeing ~36 VGPRs. That drops the need
// from 56 to ~30, which FITS the (256,6) budget of ~40 (allocator rule found
// r12-r14: per-wave cap = 256/min_waves; asking for waves the live-set can't
// fit triggers spill, not a polite clamp). Canary: WRITE_SIZE ~86 MB, no
// scratch; if spill reappears, revert to (256,4).
template <bool VT16, bool SORT>
__global__ __launch_bounds__(256, 6)
void k_sample(const float* __restrict__ xin, const void* __restrict__ vtp,
              const int* __restrict__ perm,
              __hip_bfloat16* __restrict__ fbuf, int m, int nblk) {
    __shared__ __align__(16) __hip_bfloat16 rowbuf[4][896];  // 864 + pad

    // bijective XCD swizzle: contiguous chunk of sorted points per XCD
    int b = blockIdx.x;
    {
        const int qd = nblk >> 3, r = nblk & 7;
        const int xcd = b & 7, i = b >> 3;
        b = (xcd < r) ? xcd * (qd + 1) + i : r * (qd + 1) + (xcd - r) * qd + i;
    }
    const int lane = threadIdx.x & 63;
    const int wv   = threadIdx.x >> 6;
    const int sp = b * 4 + wv;
    if (sp >= m) return;
    const int p = SORT ? perm[sp] : sp;

    const float px = xin[p * 3 + 0];
    const float py = xin[p * 3 + 1];
    const float pz = xin[p * 3 + 2];

    const int pr  = lane & 15;         // channel pair
    const int cxb = (lane >> 4) & 1;   // x corner
    const int cyb = (lane >> 5) & 1;   // y corner

    const float pxs = px * 31.5f + 31.5f;
    const float pys = py * 31.5f + 31.5f;
    const float pzs = pz * 31.5f + 31.5f;

    const int XS  = VT16 ? 6 : 7;
    const int YS  = VT16 ? 12 : 13;
    const int ZS  = VT16 ? 18 : 19;
    const int QS  = VT16 ? 24 : 25;
    const int PRB = VT16 ? 4 : 8;      // bytes per channel pair

    int   xoS[4][3], yoS[4][3], zoS[4][3], zdS[4][3];
    float wxS[4][3], wyS[4][3], wzS[4][3];
#pragma unroll
    for (int q = 0; q < 4; ++q) {
        const float sc31 = (float)(2 << q) * (31.5f / 64.0f);
#pragma unroll
        for (int pos = 0; pos < 3; ++pos) {
            const float gv = (-2.0f + 1.5f * (float)pos) * sc31;  // compile-time
            {   // x axis: per-lane (corner bit4, channel pr)
                float ix = fminf(fmaxf(pxs + gv, 0.f), 63.f);
                float xf = floorf(ix); int x0 = (int)xf; float fx = ix - xf;
                int x1 = min(x0 + 1, 63);
                xoS[q][pos] = ((cxb ? x1 : x0) << XS) + pr * PRB;
                wxS[q][pos] = cxb ? fx : 1.f - fx;
            }
            {   // y axis: per-lane (corner bit5)
                float iy = fminf(fmaxf(pys + gv, 0.f), 63.f);
                float yf = floorf(iy); int y0 = (int)yf; float fy = iy - yf;
                int y1 = min(y0 + 1, 63);
                yoS[q][pos] = (cyb ? y1 : y0) << YS;
                wyS[q][pos] = cyb ? fy : 1.f - fy;
            }
            {   // z axis: WAVE-UNIFORM -> SGPR via readfirstlane (frees 36 VGPR)
                float iz = fminf(fmaxf(pzs + gv, 0.f), 63.f);
                float zf = floorf(iz); int z0 = (int)zf; float fz = iz - zf;
                int z1 = min(z0 + 1, 63);
                zoS[q][pos] = __builtin_amdgcn_readfirstlane((z0 << ZS) + (q << QS));
                zdS[q][pos] = __builtin_amdgcn_readfirstlane((z1 - z0) << ZS);
                wzS[q][pos] = __uint_as_float(
                    __builtin_amdgcn_readfirstlane(__float_as_uint(fz)));
            }
        }
    }

    // SRSRC for vt (wave-uniform base; per-lane 32-bit voffset)
    int32x4 srsrc;
    srsrc.x = (int)(unsigned)(uintptr_t)vtp;
    srsrc.y = (int)((uintptr_t)vtp >> 32);
    srsrc.z = -1;                            // bounds check off
    srsrc.w = 0x00020000;                    // raw dword access

    const char* __restrict__ vtb = (const char*)vtp;
#pragma unroll
    for (int j = 0; j < 3; ++j)
#pragma unroll
    for (int i = 0; i < 3; ++i) {
        int   yxo[4];
        float wyx[4];
#pragma unroll
        for (int q = 0; q < 4; ++q) {
            yxo[q] = yoS[q][i] + xoS[q][j];
            wyx[q] = wyS[q][i] * wxS[q][j];
        }
#pragma unroll
        for (int k = 0; k < 3; ++k) {
            f32x2 acc = {0.f, 0.f};
#pragma unroll
            for (int q = 0; q < 4; ++q) {
                const int a0 = zoS[q][k] + yxo[q];
                const int a1 = a0 + zdS[q][k];
                f32x2 r0, r1;
                if (VT16) {
                    const unsigned u0 = llvm_amdgcn_raw_buffer_load_u32(srsrc, a0, 0, 0);
                    const unsigned u1 = llvm_amdgcn_raw_buffer_load_u32(srsrc, a1, 0, 0);
                    r0.x = __uint_as_float(u0 << 16);
                    r0.y = __uint_as_float(u0 & 0xffff0000u);
                    r1.x = __uint_as_float(u1 << 16);
                    r1.y = __uint_as_float(u1 & 0xffff0000u);
                } else {
                    r0 = *(const f32x2*)(vtb + a0);
                    r1 = *(const f32x2*)(vtb + a1);
                }
                const float fz = wzS[q][k];
                const f32x2 fz2  = {fz, fz};
                const f32x2 wyx2 = {wyx[q], wyx[q]};
                const f32x2 t = r0 + (r1 - r0) * fz2;   // z-lerp
                acc = acc + t * wyx2;
            }
            float ax = acc.x, ay = acc.y;
            ax += __shfl_xor(ax, 16); ax += __shfl_xor(ax, 32);
            ay += __shfl_xor(ay, 16); ay += __shfl_xor(ay, 32);
            if (lane < 16) {
                unsigned u;
                asm("v_cvt_pk_bf16_f32 %0, %1, %2" : "=v"(u) : "v"(ax), "v"(ay));
                ((unsigned*)&rowbuf[wv][0])[(j * 9 + i * 3 + k) * 16 + pr] = u;
            }
        }
    }

    // dense row write, NON-TEMPORAL (r7: fixed 10x write-amp + L2 thrash)
    {
        const f32x4* __restrict__ lsrc = (const f32x4*)&rowbuf[wv][0];
        f32x4* __restrict__ gdst = (f32x4*)(fbuf + (size_t)sp * 864);
#pragma unroll
        for (int r = 0; r < 2; ++r) {
            const int idx = r * 64 + lane;
            if (idx < 108) __builtin_nontemporal_store(lsrc[idx], &gdst[idx]);
        }
    }
}

// ============ MLP kernel v4: 32 points/block, 512 threads, 8 waves (r11) ============
template <bool SORT>
__global__ __launch_bounds__(512, 4)
void k_mlp(const float* __restrict__ xin, const __hip_bfloat16* __restrict__ fbuf,
           const int* __restrict__ perm,
           const __hip_bfloat16* __restrict__ w0f, const float* __restrict__ b0,
           const __hip_bfloat16* __restrict__ w1f, const float* __restrict__ b1,
           const float* __restrict__ fc1w, const float* __restrict__ fc1b,
           const __hip_bfloat16* __restrict__ w2f, const float* __restrict__ b2,
           const __hip_bfloat16* __restrict__ w3f, const float* __restrict__ b3,
           const __hip_bfloat16* __restrict__ w4f, const float* __restrict__ fc4b,
           float* __restrict__ out, int m) {
    __shared__ __align__(16) __hip_bfloat16 zcat[32][ZC_PAD];   // 16.9 KB
    __shared__ __align__(16) __hip_bfloat16 z0l[32][Z0_PAD];    //  4.6 KB
    __shared__ __align__(16) char shr[32 * 1744];               // 55.8 KB union
    __hip_bfloat16 (*rowA)[872]  = (__hip_bfloat16(*)[872])shr;            // stage+conv
    __hip_bfloat16 (*z2l)[Z2_PAD] = (__hip_bfloat16(*)[Z2_PAD])shr;        // fc2+
    __hip_bfloat16 (*z3l)[Z3_PAD] = (__hip_bfloat16(*)[Z3_PAD])(shr + 33280);

    const int tid  = threadIdx.x;
    const int wave = tid >> 6;     // 0..7
    const int lane = tid & 63;
    const int p0   = blockIdx.x * 32;
    const int row  = lane & 15, g = lane >> 4;

    // ---- stage 32 fbuf rows -> rowA (padded stride 872; 2-way bank alias) ----
    {
        const int rrow = (wave << 2) + (lane >> 4);   // 0..31
        const int srow = min(p0 + rrow, m - 1);
        const f32x4* __restrict__ src = (const f32x4*)(fbuf + (size_t)srow * 864);
        const int c16 = lane & 15;
#pragma unroll
        for (int k = 0; k < 7; ++k) {
            const int chunk = c16 + k * 16;
            if (chunk < 108)
                *(f32x4*)&rowA[rrow][chunk * 8] = src[chunk];
        }
    }

    // ---- fc1: z_point -> zcat[:,0:128] ----
    {
        const int ptp = tid >> 4;       // 0..31
        const int og  = tid & 15;
        const int sp  = min(p0 + ptp, m - 1);
        const int p   = SORT ? perm[sp] : sp;
        const float qx = xin[p * 3 + 0], qy = xin[p * 3 + 1], qz = xin[p * 3 + 2];
#pragma unroll
        for (int r = 0; r < 8; ++r) {
            const int o = og * 8 + r;
            float v = qx * fc1w[o * 3 + 0] + qy * fc1w[o * 3 + 1] + qz * fc1w[o * 3 + 2] + fc1b[o];
            v = fmaxf(v, 0.2f * v);
            zcat[ptp][o] = __float2bfloat16(v);
        }
    }
    __syncthreads();

    // ---- conv [32x864]x[864x64]: wave = (wr:2 rows) x (wc:4 cols); A from LDS ----
    {
        const int wc = wave & 3, wr = wave >> 2;
        f32x4 acc = {0.f, 0.f, 0.f, 0.f};
#pragma unroll
        for (int ks = 0; ks < 27; ++ks) {
            short8 af = *(const short8*)&rowA[wr * 16 + row][ks * 32 + g * 8];
            short8 bf = *(const short8*)(w0f + (((size_t)wc * 27 + ks) * 64 + lane) * 8);
            acc = __builtin_amdgcn_mfma_f32_16x16x32_bf16(af, bf, acc, 0, 0, 0);
        }
        const int o = wc * 16 + row;
        const float bias = b0[o];
#pragma unroll
        for (int r = 0; r < 4; ++r)
            z0l[wr * 16 + g * 4 + r][o] = __float2bfloat16(acc[r] + bias);
    }
    __syncthreads();

    // ---- lfc [32x64]x[64x128]: tc = wave; B reused across 2 row-tiles ----
    {
        const int tc = wave;
        f32x4 acc0 = {0.f, 0.f, 0.f, 0.f}, acc1 = {0.f, 0.f, 0.f, 0.f};
#pragma unroll
        for (int ks = 0; ks < 2; ++ks) {
            short8 bf = *(const short8*)(w1f + (((size_t)tc * 2 + ks) * 64 + lane) * 8);
            short8 a0 = *(const short8*)&z0l[row][ks * 32 + g * 8];
            short8 a1 = *(const short8*)&z0l[16 + row][ks * 32 + g * 8];
            acc0 = __builtin_amdgcn_mfma_f32_16x16x32_bf16(a0, bf, acc0, 0, 0, 0);
            acc1 = __builtin_amdgcn_mfma_f32_16x16x32_bf16(a1, bf, acc1, 0, 0, 0);
        }
        const int o = tc * 16 + row;
        const float bias = b1[o];
#pragma unroll
        for (int r = 0; r < 4; ++r) {
            zcat[g * 4 + r][128 + o]      = __float2bfloat16(acc0[r] + bias);
            zcat[16 + g * 4 + r][128 + o] = __float2bfloat16(acc1[r] + bias);
        }
    }
    __syncthreads();

    // ---- fc2 [32x256]x[256x512]: tc = wave*4+c; A loaded once per (ks,tr) ----
    {
        f32x4 acc[4][2];
#pragma unroll
        for (int c = 0; c < 4; ++c)
#pragma unroll
            for (int t = 0; t < 2; ++t) acc[c][t] = (f32x4){0.f, 0.f, 0.f, 0.f};
#pragma unroll
        for (int ks = 0; ks < 8; ++ks) {
            short8 a0 = *(const short8*)&zcat[row][ks * 32 + g * 8];
            short8 a1 = *(const short8*)&zcat[16 + row][ks * 32 + g * 8];
#pragma unroll
            for (int c = 0; c < 4; ++c) {
                short8 bf = *(const short8*)(w2f + (((size_t)(wave * 4 + c) * 8 + ks) * 64 + lane) * 8);
                acc[c][0] = __builtin_amdgcn_mfma_f32_16x16x32_bf16(a0, bf, acc[c][0], 0, 0, 0);
                acc[c][1] = __builtin_amdgcn_mfma_f32_16x16x32_bf16(a1, bf, acc[c][1], 0, 0, 0);
            }
        }
#pragma unroll
        for (int c = 0; c < 4; ++c) {
            const int o = (wave * 4 + c) * 16 + row;
            const float bias = b2[o];
#pragma unroll
            for (int r = 0; r < 4; ++r) {
                float v0 = acc[c][0][r] + bias; v0 = fmaxf(v0, 0.2f * v0);
                float v1 = acc[c][1][r] + bias; v1 = fmaxf(v1, 0.2f * v1);
                z2l[g * 4 + r][o]      = __float2bfloat16(v0);
                z2l[16 + g * 4 + r][o] = __float2bfloat16(v1);
            }
        }
    }
    __syncthreads();

    // ---- fc3 [32x512]x[512x256]: tc = wave*2+c ----
    {
        f32x4 acc[2][2];
#pragma unroll
        for (int c = 0; c < 2; ++c)
#pragma unroll
            for (int t = 0; t < 2; ++t) acc[c][t] = (f32x4){0.f, 0.f, 0.f, 0.f};
#pragma unroll
        for (int ks = 0; ks < 16; ++ks) {
            short8 a0 = *(const short8*)&z2l[row][ks * 32 + g * 8];
            short8 a1 = *(const short8*)&z2l[16 + row][ks * 32 + g * 8];
#pragma unroll
            for (int c = 0; c < 2; ++c) {
                short8 bf = *(const short8*)(w3f + (((size_t)(wave * 2 + c) * 16 + ks) * 64 + lane) * 8);
                acc[c][0] = __builtin_amdgcn_mfma_f32_16x16x32_bf16(a0, bf, acc[c][0], 0, 0, 0);
                acc[c][1] = __builtin_amdgcn_mfma_f32_16x16x32_bf16(a1, bf, acc[c][1], 0, 0, 0);
            }
        }
#pragma unroll
        for (int c = 0; c < 2; ++c) {
            const int o = (wave * 2 + c) * 16 + row;
            const float bias = b3[o];
#pragma unroll
            for (int r = 0; r < 4; ++r) {
                float v0 = acc[c][0][r] + bias; v0 = fmaxf(v0, 0.2f * v0);
                float v1 = acc[c][1][r] + bias; v1 = fmaxf(v1, 0.2f * v1);
                z3l[g * 4 + r][o]      = __float2bfloat16(v0);
                z3l[16 + g * 4 + r][o] = __float2bfloat16(v1);
            }
        }
    }
    __syncthreads();

    // ---- fc4 [32x256]x[256x16(pad)]: waves 0..1 (tr = wave), 8 MFMA each ----
    if (wave < 2) {
        f32x4 acc = {0.f, 0.f, 0.f, 0.f};
#pragma unroll
        for (int ks = 0; ks < 8; ++ks) {
            short8 af = *(const short8*)&z3l[wave * 16 + row][ks * 32 + g * 8];
            short8 bf = *(const short8*)(w4f + (((size_t)ks) * 64 + lane) * 8);
            acc = __builtin_amdgcn_mfma_f32_16x16x32_bf16(af, bf, acc, 0, 0, 0);
        }
        const int o = row;
        if (o < 3) {
            const float bias = fc4b[o];
#pragma unroll
            for (int r = 0; r < 4; ++r) {
                const int spg = p0 + wave * 16 + g * 4 + r;
                if (spg < m) {
                    const int pg = SORT ? perm[spg] : spg;
                    out[pg * 3 + o] = acc[r] + bias;
                }
            }
        }
    }
}

extern "C" void kernel_launch(void* const* d_in, const int* in_sizes, int n_in,
                              void* d_out, int out_size, void* d_ws, size_t ws_size,
                              hipStream_t stream) {
    const float* x      = (const float*)d_in[1];
    const float* v0     = (const float*)d_in[2];
    const float* v1     = (const float*)d_in[3];
    const float* v2     = (const float*)d_in[4];
    const float* v3     = (const float*)d_in[5];
    const float* conv_w = (const float*)d_in[6];
    const float* conv_b = (const float*)d_in[7];
    const float* lfc_w  = (const float*)d_in[8];
    const float* lfc_b  = (const float*)d_in[9];
    const float* fc1_w  = (const float*)d_in[10];
    const float* fc1_b  = (const float*)d_in[11];
    const float* fc2_w  = (const float*)d_in[12];
    const float* fc2_b  = (const float*)d_in[13];
    const float* fc3_w  = (const float*)d_in[14];
    const float* fc3_b  = (const float*)d_in[15];
    const float* fc4_w  = (const float*)d_in[16];
    const float* fc4_b  = (const float*)d_in[17];
    float* out = (float*)d_out;
    const int m = in_sizes[1] / 3;

    char* ws = (char*)d_ws;
    size_t woff = 0;
    __hip_bfloat16* w0f = (__hip_bfloat16*)(ws + woff); woff += (size_t)55296 * 2;
    __hip_bfloat16* w1f = (__hip_bfloat16*)(ws + woff); woff += (size_t)8192 * 2;
    __hip_bfloat16* w2f = (__hip_bfloat16*)(ws + woff); woff += (size_t)131072 * 2;
    __hip_bfloat16* w3f = (__hip_bfloat16*)(ws + woff); woff += (size_t)131072 * 2;
    __hip_bfloat16* w4f = (__hip_bfloat16*)(ws + woff); woff += (size_t)4096 * 2;
    woff = (woff + 255) & ~(size_t)255;
    int* hist   = (int*)(ws + woff); woff += NCELL * 4;
    int* cursor = (int*)(ws + woff); woff += NCELL * 4;
    int* perm   = (int*)(ws + woff); woff += ((size_t)m * 4 + 255) & ~(size_t)255;

    const size_t vt32_bytes = (size_t)4 * VOXELS * 32 * 4;   // 128 MiB
    const size_t vt16_bytes = (size_t)4 * VOXELS * 32 * 2;   // 64 MiB
    const size_t fbytes     = ((size_t)m * 864 * 2 + 255) & ~(size_t)255;

    const size_t need_split16 = woff + vt16_bytes + fbytes;
    const size_t need_split32 = woff + vt32_bytes + fbytes;

    k_prepw_all<<<(329728 + 255) / 256, 256, 0, stream>>>(conv_w, lfc_w, fc2_w, fc3_w, fc4_w,
                                                          w0f, w1f, w2f, w3f, w4f);

    const int nsb = (m + 3) / 4;
    const int nb  = (m + 31) / 32;
    const int npb = (m + 255) / 256;

    if (ws_size >= need_split16) {
        // ---- preferred: bf16 channel-last vt + Morton sort ----
        void* vt = (void*)(ws + woff);
        __hip_bfloat16* fbuf = (__hip_bfloat16*)(ws + woff + vt16_bytes);
        hipMemsetAsync(hist, 0, NCELL * 4, stream);
        k_hist<<<npb, 256, 0, stream>>>(x, hist, m);
        k_scan<<<1, 64, 0, stream>>>(hist, cursor);
        k_scatter<<<npb, 256, 0, stream>>>(x, cursor, perm, m);
        k_transpose<true><<<16384, 256, 0, stream>>>(v0, v1, v2, v3, vt);
        k_sample<true, true><<<nsb, 256, 0, stream>>>(x, vt, perm, fbuf, m, nsb);
        k_mlp<true><<<nb, 512, 0, stream>>>(x, fbuf, perm, w0f, conv_b, w1f, lfc_b,
                                            fc1_w, fc1_b, w2f, fc2_b, w3f, fc3_b,
                                            w4f, fc4_b, out, m);
    } else if (ws_size >= need_split32) {
        void* vt = (void*)(ws + woff);
        __hip_bfloat16* fbuf = (__hip_bfloat16*)(ws + woff + vt32_bytes);
        hipMemsetAsync(hist, 0, NCELL * 4, stream);
        k_hist<<<npb, 256, 0, stream>>>(x, hist, m);
        k_scan<<<1, 64, 0, stream>>>(hist, cursor);
        k_scatter<<<npb, 256, 0, stream>>>(x, cursor, perm, m);
        k_transpose<false><<<16384, 256, 0, stream>>>(v0, v1, v2, v3, vt);
        k_sample<false, true><<<nsb, 256, 0, stream>>>(x, vt, perm, fbuf, m, nsb);
        k_mlp<true><<<nb, 512, 0, stream>>>(x, fbuf, perm, w0f, conv_b, w1f, lfc_b,
                                            fc1_w, fc1_b, w2f, fc2_b, w3f, fc3_b,
                                            w4f, fc4_b, out, m);
    } else {
        __hip_bfloat16* fbuf = (__hip_bfloat16*)(ws + woff);
        k_sample<false, false><<<nsb, 256, 0, stream>>>(x, nullptr, perm, fbuf, m, nsb);
        k_mlp<false><<<nb, 512, 0, stream>>>(x, fbuf, perm, w0f, conv_b, w1f, lfc_b,
                                             fc1_w, fc1_b, w2f, fc2_b, w3f, fc3_b,
                                             w4f, fc4_b, out, m);
    }
}